// Round 2
// baseline (338.259 us; speedup 1.0000x reference)
//
#include <hip/hip_runtime.h>
#include <math.h>

#define DIM 128

typedef float f32x4v __attribute__((ext_vector_type(4)));
typedef short bf16x8 __attribute__((ext_vector_type(8)));

static __device__ __forceinline__ short f2bf(float f) {
    unsigned u = __float_as_uint(f);
    unsigned r = (u + 0x7fffu + ((u >> 16) & 1u)) >> 16;   // RNE
    return (short)r;
}
static __device__ __forceinline__ float bf2f(unsigned short s) {
    return __uint_as_float(((unsigned)s) << 16);
}

// ---------------------------------------------------------------------------
// K1: degree histogram with 4-way replicated counters to cut TCC same-line
// atomic contention. degR layout: [r*N+n] r=0..3 -> degO, r=4..7 -> degI.
__global__ __launch_bounds__(256) void k_deg(const int* __restrict__ src,
                                             const int* __restrict__ dst,
                                             int* degR, int N, int E) {
    int e = blockIdx.x * 256 + threadIdx.x;
    if (e < E) {
        int r = threadIdx.x & 3;
        atomicAdd(&degR[r * N + src[e]], 1);
        atomicAdd(&degR[(4 + r) * N + dst[e]], 1);
    }
}

// K2: per-1024-chunk sums of degI (over replicas).
__global__ __launch_bounds__(256) void k_bsum(const int* __restrict__ degR,
                                              int* __restrict__ bsum, int N) {
    __shared__ int red[4];
    int b = blockIdx.x, t = threadIdx.x;
    int idx = b * 1024 + t * 4;
    int s = 0;
    #pragma unroll
    for (int r = 4; r < 8; ++r) {
        const int* dI = degR + r * N;
        for (int j = 0; j < 4; ++j) if (idx + j < N) s += dI[idx + j];
    }
    for (int off = 32; off; off >>= 1) s += __shfl_down(s, off);
    if ((t & 63) == 0) red[t >> 6] = s;
    __syncthreads();
    if (t == 0) bsum[b] = red[0] + red[1] + red[2] + red[3];
}

// K3: per-chunk exclusive scan -> csrOff + cursor (wave 0 re-scans bsums).
__global__ __launch_bounds__(256) void k_off(const int* __restrict__ degR,
                                             const int* __restrict__ bsum,
                                             int* __restrict__ csrOff,
                                             int* __restrict__ cursor,
                                             int N, int NB) {
    __shared__ int sp[256];
    __shared__ int sbase;
    int b = blockIdx.x, t = threadIdx.x;
    if (t < 64) {
        int own = (t < NB) ? bsum[t] : 0;
        int v = own;
        for (int off = 1; off < 64; off <<= 1) {
            int u = __shfl_up(v, off);
            if (t >= off) v += u;
        }
        if (t == b) sbase = v - own;
        if (b == 0 && t == NB - 1) { csrOff[N] = v; cursor[N] = v; }
    }
    __syncthreads();
    int idx = b * 1024 + t * 4;
    int va[4] = {0, 0, 0, 0};
    #pragma unroll
    for (int r = 4; r < 8; ++r) {
        const int* dI = degR + r * N;
        for (int j = 0; j < 4; ++j) if (idx + j < N) va[j] += dI[idx + j];
    }
    int s = va[0] + va[1] + va[2] + va[3];
    sp[t] = s;
    __syncthreads();
    for (int off = 1; off < 256; off <<= 1) {
        int u = (t >= off) ? sp[t - off] : 0;
        __syncthreads();
        sp[t] += u;
        __syncthreads();
    }
    int o = sbase + sp[t] - s;
    for (int j = 0; j < 4; ++j) {
        if (idx + j < N) { csrOff[idx + j] = o; cursor[idx + j] = o; }
        o += va[j];
    }
}

// K4: merged normI + pre-scaled bf16 feat/hx + bf16 weight convert.
__global__ __launch_bounds__(256) void k_xcw(const float* __restrict__ feat,
                                             const float* __restrict__ hx,
                                             const float* __restrict__ Wi,
                                             const float* __restrict__ Wh,
                                             const int* __restrict__ degR,
                                             float* __restrict__ normIf,
                                             short* __restrict__ Wbf,
                                             short* __restrict__ fh, int N) {
    int i = blockIdx.x * 256 + threadIdx.x;
    int T1 = N * 64, T2 = N * 64 + N;
    if (i < T1) {
        int n = i >> 6, q = i & 63;
        int dO = degR[n] + degR[N + n] + degR[2 * N + n] + degR[3 * N + n];
        float ns = rsqrtf(fmaxf((float)dO, 1.0f));
        const float* spp = (q < 32) ? &feat[(size_t)n * 128 + q * 4]
                                    : &hx[(size_t)n * 128 + (q - 32) * 4];
        float4 v = *(const float4*)spp;
        short4 p;
        p.x = f2bf(v.x * ns); p.y = f2bf(v.y * ns);
        p.z = f2bf(v.z * ns); p.w = f2bf(v.w * ns);
        *(short4*)&fh[(size_t)n * 256 + q * 4] = p;   // q*4 == 128+(q-32)*4
    } else if (i < T2) {
        int n = i - T1;
        int dI = degR[4 * N + n] + degR[5 * N + n] + degR[6 * N + n] + degR[7 * N + n];
        normIf[n] = rsqrtf(fmaxf((float)dI, 1.0f));
    } else if (i < T2 + 98304) {
        int w = i - T2;
        int k = w & 127, n = (w >> 7) & 15, r = w >> 11;
        int gm = r % 6, cb = r / 6;
        const float* Wsrc = (gm < 3) ? Wi : Wh;
        int g = gm % 3;
        Wbf[w] = f2bf(Wsrc[k * 384 + g * 128 + cb * 16 + n]);
    }
}

// K5: counting-sort fill: srcSorted grouped by dst.
__global__ __launch_bounds__(256) void k_fill(const int* __restrict__ src,
                                              const int* __restrict__ dst,
                                              int* cursor, int* __restrict__ srcSorted,
                                              int E) {
    int e = blockIdx.x * 256 + threadIdx.x;
    if (e < E) {
        int pos = atomicAdd(&cursor[dst[e]], 1);
        srcSorted[pos] = src[e];
    }
}

// ---------------------------------------------------------------------------
// K6: gather-aggregate. One wave per dst node, no LDS.
// NEW (this round): two edges per wave iteration — lanes 0-31 read edge e,
// lanes 32-63 read edge e+1, 16 B/lane (dwordx4) -> 1 KB per load instr
// covering 2 rows, half the loop trips, 2x bytes in flight per unroll step.
// Half-wave partials combined with 8 shfl_xor(32) at the end; lanes 0-31
// store 16 B each. fp32 accumulate + bf16 RNE pack unchanged.
__global__ __launch_bounds__(256) void gather_kernel(
    const short* __restrict__ fh, const int* __restrict__ csrOff,
    const int* __restrict__ srcSorted, const float* __restrict__ normIf,
    short* __restrict__ agg, int N) {
    int wv = threadIdx.x >> 6, lane = threadIdx.x & 63;
    int d = blockIdx.x * 4 + wv;
    if (d >= N) return;
    int half = lane >> 5;        // 0: even edges, 1: odd edges
    int l32 = lane & 31;
    int beg = csrOff[d], end = csrOff[d + 1];
    int deg = end - beg;
    float acc[8] = {0.f, 0.f, 0.f, 0.f, 0.f, 0.f, 0.f, 0.f};
    int nPair = deg >> 1;
    int eBase = beg + half;
    #pragma unroll 8
    for (int p = 0; p < nPair; ++p) {
        int s = srcSorted[eBase + 2 * p];
        uint4 v = *(const uint4*)(fh + (size_t)s * 256 + l32 * 8);   // 16 B
        acc[0] += __uint_as_float(v.x << 16);
        acc[1] += __uint_as_float(v.x & 0xffff0000u);
        acc[2] += __uint_as_float(v.y << 16);
        acc[3] += __uint_as_float(v.y & 0xffff0000u);
        acc[4] += __uint_as_float(v.z << 16);
        acc[5] += __uint_as_float(v.z & 0xffff0000u);
        acc[6] += __uint_as_float(v.w << 16);
        acc[7] += __uint_as_float(v.w & 0xffff0000u);
    }
    if (deg & 1) {
        if (half == 0) {          // tail edge: half-wave, one-time divergence
            int s = srcSorted[end - 1];
            uint4 v = *(const uint4*)(fh + (size_t)s * 256 + l32 * 8);
            acc[0] += __uint_as_float(v.x << 16);
            acc[1] += __uint_as_float(v.x & 0xffff0000u);
            acc[2] += __uint_as_float(v.y << 16);
            acc[3] += __uint_as_float(v.y & 0xffff0000u);
            acc[4] += __uint_as_float(v.z << 16);
            acc[5] += __uint_as_float(v.z & 0xffff0000u);
            acc[6] += __uint_as_float(v.w << 16);
            acc[7] += __uint_as_float(v.w & 0xffff0000u);
        }
    }
    #pragma unroll
    for (int i = 0; i < 8; ++i) acc[i] += __shfl_xor(acc[i], 32);
    if (half == 0) {
        float nd = normIf[d];
        bf16x8 pk;
        #pragma unroll
        for (int i = 0; i < 8; ++i) pk[i] = f2bf(acc[i] * nd);
        *(bf16x8*)&agg[(size_t)d * 256 + l32 * 8] = pk;
    }
}

// ---------------------------------------------------------------------------
// K7: dense bf16 MFMA GEMM + GRU gates. Weights staged per-cb into LDS via
// global_load_lds (width=16), double-buffered, shared by the 4 waves of the
// block. LDS layout XOR-swizzled (16B slot ^= row&15) on BOTH the global
// source address and the LDS read address -> bank-conflict-free ds_read_b128
// with bit-identical per-lane fragments.
#define GLOAD_LDS16(gp, lp)                                                   \
    __builtin_amdgcn_global_load_lds(                                         \
        (const __attribute__((address_space(1))) void*)(gp),                  \
        (__attribute__((address_space(3))) void*)(lp), 16, 0, 0)

__global__ __launch_bounds__(256, 3) void gemm_gates_kernel(
    const short* __restrict__ agg, const float* __restrict__ hx,
    const short* __restrict__ Wbf,
    const float* __restrict__ bi, const float* __restrict__ bh,
    float* __restrict__ out, int N) {
    __shared__ short wlds[2][12288];            // 2 x 24.6 KB double buffer
    const int tid = threadIdx.x;
    const int wv = tid >> 6, lane = tid & 63;
    const int l15 = lane & 15, quad = lane >> 4;
    const int rowBase = (blockIdx.x * 4 + wv) * 16;
    // N is a multiple of 16, so an active wave always has 16 valid rows.
    // Inactive waves (tail block) must still stage + hit barriers.
    const bool active = rowBase < N;

    // A-fragments preloaded to registers BEFORE any out store (agg aliases
    // out; each wave reads/writes only its own 16 rows -> no hazard).
    int arow = active ? rowBase + l15 : 0;
    const short* aPtr = agg + (size_t)arow * 256;
    bf16x8 aLo[4], aHi[4];
    #pragma unroll
    for (int kst = 0; kst < 4; ++kst) {
        aLo[kst] = *(const bf16x8*)&aPtr[kst * 32 + quad * 8];
        aHi[kst] = *(const bf16x8*)&aPtr[128 + kst * 32 + quad * 8];
    }

    // Prologue: stage cb=0 slab (each wave copies its own 6144 B chunk).
    {
        const char* gs = (const char*)Wbf;
        #pragma unroll
        for (int i = 0; i < 6; ++i) {
            int ldsByte = wv * 6144 + i * 1024 + lane * 16;
            int gByte = ldsByte ^ (((ldsByte >> 8) & 15) << 4);   // slot ^= row&15
            GLOAD_LDS16(gs + gByte, (char*)&wlds[0][0] + wv * 6144 + i * 1024);
        }
    }
    __syncthreads();   // compiler drains vmcnt(0) before s_barrier

    for (int cb = 0; cb < 8; ++cb) {
        const int buf = cb & 1;
        if (cb < 7) {   // async prefetch next slab into the other buffer
            const char* gs = (const char*)(Wbf + (size_t)(cb + 1) * 12288);
            #pragma unroll
            for (int i = 0; i < 6; ++i) {
                int ldsByte = wv * 6144 + i * 1024 + lane * 16;
                int gByte = ldsByte ^ (((ldsByte >> 8) & 15) << 4);
                GLOAD_LDS16(gs + gByte,
                            (char*)&wlds[buf ^ 1][0] + wv * 6144 + i * 1024);
            }
        }
        if (active) {
            f32x4v acc[6];
            #pragma unroll
            for (int g = 0; g < 6; ++g) acc[g] = (f32x4v){0.f, 0.f, 0.f, 0.f};
            const char* slab = (const char*)&wlds[buf][0];
            #pragma unroll
            for (int kst = 0; kst < 4; ++kst) {
                const int co = (((kst * 4 + quad) ^ l15) << 4);   // swizzled col
                #pragma unroll
                for (int g = 0; g < 3; ++g) {
                    bf16x8 bI = *(const bf16x8*)(slab + g * 4096 + l15 * 256 + co);
                    acc[g] = __builtin_amdgcn_mfma_f32_16x16x32_bf16(
                        aLo[kst], bI, acc[g], 0, 0, 0);
                    bf16x8 bH = *(const bf16x8*)(slab + (g + 3) * 4096 + l15 * 256 + co);
                    acc[g + 3] = __builtin_amdgcn_mfma_f32_16x16x32_bf16(
                        aHi[kst], bH, acc[g + 3], 0, 0, 0);
                }
            }
            int ocol = cb * 16 + l15;
            float bir = bi[ocol], biz = bi[128 + ocol], bin = bi[256 + ocol];
            float bhr = bh[ocol], bhz = bh[128 + ocol], bhn = bh[256 + ocol];
            #pragma unroll
            for (int reg = 0; reg < 4; ++reg) {
                int row = rowBase + quad * 4 + reg;
                float ir = acc[0][reg] + bir, iz = acc[1][reg] + biz, in_ = acc[2][reg] + bin;
                float hr = acc[3][reg] + bhr, hz = acc[4][reg] + bhz, hn = acc[5][reg] + bhn;
                float rg = 1.0f / (1.0f + __expf(-(ir + hr)));
                float zg = 1.0f / (1.0f + __expf(-(iz + hz)));
                float ng = tanhf(in_ + rg * hn);
                float hv = hx[(size_t)row * DIM + ocol];
                out[(size_t)row * DIM + ocol] = (1.0f - zg) * ng + zg * hv;
            }
        }
        __syncthreads();   // drains this iter's prefetch; protects buf reuse
    }
}

// ---------------------------------------------------------------------------
extern "C" void kernel_launch(void* const* d_in, const int* in_sizes, int n_in,
                              void* d_out, int out_size, void* d_ws, size_t ws_size,
                              hipStream_t stream) {
    const float* feat = (const float*)d_in[0];
    const float* hx   = (const float*)d_in[1];
    const float* Wi   = (const float*)d_in[2];
    const float* bi   = (const float*)d_in[3];
    const float* Wh   = (const float*)d_in[4];
    const float* bh   = (const float*)d_in[5];
    const int* src    = (const int*)d_in[6];
    const int* dst    = (const int*)d_in[7];
    float* out        = (float*)d_out;

    int N = in_sizes[0] / DIM;   // 50000
    int E = in_sizes[6];         // 800000
    int NB = (N + 1023) / 1024;  // 49 (<=64 required by the wave scan)

    int* wsi = (int*)d_ws;
    int* degR      = wsi;                      // 8N (4 degO + 4 degI replicas)
    int* csrOff    = wsi + 8 * N;              // N+1
    int* cursor    = wsi + 9 * N + 1;          // N+1
    int* srcSorted = wsi + 10 * N + 2;         // E
    int* bsum      = wsi + 10 * N + 2 + E;     // 64
    float* normIf  = (float*)(bsum + 64);      // N
    size_t wofs = (((size_t)(11 * N + 2 + E + 64)) * 4 + 15) & ~(size_t)15;
    short* Wbf = (short*)((char*)d_ws + wofs);         // 98304 bf16
    size_t fofs = (wofs + 98304 * 2 + 15) & ~(size_t)15;
    short* fh = (short*)((char*)d_ws + fofs);          // N*256 bf16 (~25.6MB)
    // total ws: ~31.5 MB (proven-safe budget: 51.6 MB)
    short* agg = (short*)d_out;  // bf16 agg aliased over d_out

    hipMemsetAsync(degR, 0, (size_t)(8 * N) * sizeof(int), stream);
    k_deg<<<(E + 255) / 256, 256, 0, stream>>>(src, dst, degR, N, E);
    k_bsum<<<NB, 256, 0, stream>>>(degR, bsum, N);
    k_off<<<NB, 256, 0, stream>>>(degR, bsum, csrOff, cursor, N, NB);
    k_xcw<<<(N * 65 + 98304 + 255) / 256, 256, 0, stream>>>(
        feat, hx, Wi, Wh, degR, normIf, Wbf, fh, N);
    k_fill<<<(E + 255) / 256, 256, 0, stream>>>(src, dst, cursor, srcSorted, E);

    gather_kernel<<<(N + 3) / 4, 256, 0, stream>>>(
        fh, csrOff, srcSorted, normIf, agg, N);
    gemm_gates_kernel<<<(N + 63) / 64, 256, 0, stream>>>(
        agg, hx, Wbf, bi, bh, out, N);
}

// Round 3
// 330.301 us; speedup vs baseline: 1.0241x; 1.0241x over previous
//
#include <hip/hip_runtime.h>
#include <math.h>

#define DIM 128

typedef float f32x4v __attribute__((ext_vector_type(4)));
typedef short bf16x8 __attribute__((ext_vector_type(8)));

static __device__ __forceinline__ short f2bf(float f) {
    unsigned u = __float_as_uint(f);
    unsigned r = (u + 0x7fffu + ((u >> 16) & 1u)) >> 16;   // RNE
    return (short)r;
}
static __device__ __forceinline__ float bf2f(unsigned short s) {
    return __uint_as_float(((unsigned)s) << 16);
}

// ---------------------------------------------------------------------------
// K1: degree histogram with 4-way replicated counters to cut TCC same-line
// atomic contention. degR layout: [r*N+n] r=0..3 -> degO, r=4..7 -> degI.
__global__ __launch_bounds__(256) void k_deg(const int* __restrict__ src,
                                             const int* __restrict__ dst,
                                             int* degR, int N, int E) {
    int e = blockIdx.x * 256 + threadIdx.x;
    if (e < E) {
        int r = threadIdx.x & 3;
        atomicAdd(&degR[r * N + src[e]], 1);
        atomicAdd(&degR[(4 + r) * N + dst[e]], 1);
    }
}

// K2: per-1024-chunk sums of degI (over replicas).
__global__ __launch_bounds__(256) void k_bsum(const int* __restrict__ degR,
                                              int* __restrict__ bsum, int N) {
    __shared__ int red[4];
    int b = blockIdx.x, t = threadIdx.x;
    int idx = b * 1024 + t * 4;
    int s = 0;
    #pragma unroll
    for (int r = 4; r < 8; ++r) {
        const int* dI = degR + r * N;
        for (int j = 0; j < 4; ++j) if (idx + j < N) s += dI[idx + j];
    }
    for (int off = 32; off; off >>= 1) s += __shfl_down(s, off);
    if ((t & 63) == 0) red[t >> 6] = s;
    __syncthreads();
    if (t == 0) bsum[b] = red[0] + red[1] + red[2] + red[3];
}

// K3: per-chunk exclusive scan -> csrOff + cursor (wave 0 re-scans bsums).
__global__ __launch_bounds__(256) void k_off(const int* __restrict__ degR,
                                             const int* __restrict__ bsum,
                                             int* __restrict__ csrOff,
                                             int* __restrict__ cursor,
                                             int N, int NB) {
    __shared__ int sp[256];
    __shared__ int sbase;
    int b = blockIdx.x, t = threadIdx.x;
    if (t < 64) {
        int own = (t < NB) ? bsum[t] : 0;
        int v = own;
        for (int off = 1; off < 64; off <<= 1) {
            int u = __shfl_up(v, off);
            if (t >= off) v += u;
        }
        if (t == b) sbase = v - own;
        if (b == 0 && t == NB - 1) { csrOff[N] = v; cursor[N] = v; }
    }
    __syncthreads();
    int idx = b * 1024 + t * 4;
    int va[4] = {0, 0, 0, 0};
    #pragma unroll
    for (int r = 4; r < 8; ++r) {
        const int* dI = degR + r * N;
        for (int j = 0; j < 4; ++j) if (idx + j < N) va[j] += dI[idx + j];
    }
    int s = va[0] + va[1] + va[2] + va[3];
    sp[t] = s;
    __syncthreads();
    for (int off = 1; off < 256; off <<= 1) {
        int u = (t >= off) ? sp[t - off] : 0;
        __syncthreads();
        sp[t] += u;
        __syncthreads();
    }
    int o = sbase + sp[t] - s;
    for (int j = 0; j < 4; ++j) {
        if (idx + j < N) { csrOff[idx + j] = o; cursor[idx + j] = o; }
        o += va[j];
    }
}

// K4: merged normI + pre-scaled bf16 feat/hx + bf16 weight convert.
__global__ __launch_bounds__(256) void k_xcw(const float* __restrict__ feat,
                                             const float* __restrict__ hx,
                                             const float* __restrict__ Wi,
                                             const float* __restrict__ Wh,
                                             const int* __restrict__ degR,
                                             float* __restrict__ normIf,
                                             short* __restrict__ Wbf,
                                             short* __restrict__ fh, int N) {
    int i = blockIdx.x * 256 + threadIdx.x;
    int T1 = N * 64, T2 = N * 64 + N;
    if (i < T1) {
        int n = i >> 6, q = i & 63;
        int dO = degR[n] + degR[N + n] + degR[2 * N + n] + degR[3 * N + n];
        float ns = rsqrtf(fmaxf((float)dO, 1.0f));
        const float* spp = (q < 32) ? &feat[(size_t)n * 128 + q * 4]
                                    : &hx[(size_t)n * 128 + (q - 32) * 4];
        float4 v = *(const float4*)spp;
        short4 p;
        p.x = f2bf(v.x * ns); p.y = f2bf(v.y * ns);
        p.z = f2bf(v.z * ns); p.w = f2bf(v.w * ns);
        *(short4*)&fh[(size_t)n * 256 + q * 4] = p;   // q*4 == 128+(q-32)*4
    } else if (i < T2) {
        int n = i - T1;
        int dI = degR[4 * N + n] + degR[5 * N + n] + degR[6 * N + n] + degR[7 * N + n];
        normIf[n] = rsqrtf(fmaxf((float)dI, 1.0f));
    } else if (i < T2 + 98304) {
        int w = i - T2;
        int k = w & 127, n = (w >> 7) & 15, r = w >> 11;
        int gm = r % 6, cb = r / 6;
        const float* Wsrc = (gm < 3) ? Wi : Wh;
        int g = gm % 3;
        Wbf[w] = f2bf(Wsrc[k * 384 + g * 128 + cb * 16 + n]);
    }
}

// K5: counting-sort fill: srcSorted grouped by dst.
__global__ __launch_bounds__(256) void k_fill(const int* __restrict__ src,
                                              const int* __restrict__ dst,
                                              int* cursor, int* __restrict__ srcSorted,
                                              int E) {
    int e = blockIdx.x * 256 + threadIdx.x;
    if (e < E) {
        int pos = atomicAdd(&cursor[dst[e]], 1);
        srcSorted[pos] = src[e];
    }
}

// ---------------------------------------------------------------------------
// K6: gather-aggregate. One wave per dst node, no LDS, 8 B/lane row reads
// (the R1 structure: wave-uniform scalar index loads, 28-VGPR class).
// NEW (this round): explicit 8-edge batches. The 8 indices are loaded first
// (wave-uniform -> one s_load_dwordx8 through the constant cache), then 8
// INDEPENDENT global_load_dwordx2 row loads are issued before any
// accumulate, forcing ~8 loads in flight per wave (R1's 28-VGPR encoding
// shows the compiler only kept ~2-3). Edge order of accumulation is
// unchanged -> numerics identical to R1.
__global__ __launch_bounds__(256) void gather_kernel(
    const short* __restrict__ fh, const int* __restrict__ csrOff,
    const int* __restrict__ srcSorted, const float* __restrict__ normIf,
    short* __restrict__ agg, int N) {
    int wv = threadIdx.x >> 6, lane = threadIdx.x & 63;
    int d = blockIdx.x * 4 + wv;
    if (d >= N) return;
    const ushort4* fh4 = (const ushort4*)fh;
    int beg = csrOff[d], end = csrOff[d + 1];
    float nd = normIf[d];
    float4 acc = make_float4(0.f, 0.f, 0.f, 0.f);
    int e = beg;
    for (; e + 8 <= end; e += 8) {
        int s0 = srcSorted[e + 0], s1 = srcSorted[e + 1];
        int s2 = srcSorted[e + 2], s3 = srcSorted[e + 3];
        int s4 = srcSorted[e + 4], s5 = srcSorted[e + 5];
        int s6 = srcSorted[e + 6], s7 = srcSorted[e + 7];
        ushort4 v0 = fh4[(size_t)s0 * 64 + lane];
        ushort4 v1 = fh4[(size_t)s1 * 64 + lane];
        ushort4 v2 = fh4[(size_t)s2 * 64 + lane];
        ushort4 v3 = fh4[(size_t)s3 * 64 + lane];
        ushort4 v4 = fh4[(size_t)s4 * 64 + lane];
        ushort4 v5 = fh4[(size_t)s5 * 64 + lane];
        ushort4 v6 = fh4[(size_t)s6 * 64 + lane];
        ushort4 v7 = fh4[(size_t)s7 * 64 + lane];
        acc.x += bf2f(v0.x); acc.y += bf2f(v0.y); acc.z += bf2f(v0.z); acc.w += bf2f(v0.w);
        acc.x += bf2f(v1.x); acc.y += bf2f(v1.y); acc.z += bf2f(v1.z); acc.w += bf2f(v1.w);
        acc.x += bf2f(v2.x); acc.y += bf2f(v2.y); acc.z += bf2f(v2.z); acc.w += bf2f(v2.w);
        acc.x += bf2f(v3.x); acc.y += bf2f(v3.y); acc.z += bf2f(v3.z); acc.w += bf2f(v3.w);
        acc.x += bf2f(v4.x); acc.y += bf2f(v4.y); acc.z += bf2f(v4.z); acc.w += bf2f(v4.w);
        acc.x += bf2f(v5.x); acc.y += bf2f(v5.y); acc.z += bf2f(v5.z); acc.w += bf2f(v5.w);
        acc.x += bf2f(v6.x); acc.y += bf2f(v6.y); acc.z += bf2f(v6.z); acc.w += bf2f(v6.w);
        acc.x += bf2f(v7.x); acc.y += bf2f(v7.y); acc.z += bf2f(v7.z); acc.w += bf2f(v7.w);
    }
    for (; e < end; ++e) {
        int s = srcSorted[e];                     // wave-uniform scalar load
        ushort4 v = fh4[(size_t)s * 64 + lane];   // 8B/lane, 512B/wave
        acc.x += bf2f(v.x); acc.y += bf2f(v.y);
        acc.z += bf2f(v.z); acc.w += bf2f(v.w);
    }
    short4 p;
    p.x = f2bf(acc.x * nd); p.y = f2bf(acc.y * nd);
    p.z = f2bf(acc.z * nd); p.w = f2bf(acc.w * nd);
    *(short4*)&agg[(size_t)d * 256 + lane * 4] = p;
}

// ---------------------------------------------------------------------------
// K7: dense bf16 MFMA GEMM + GRU gates. Weights staged per-cb into LDS via
// global_load_lds (width=16), double-buffered, shared by the 4 waves of the
// block. LDS layout XOR-swizzled (16B slot ^= row&15) on BOTH the global
// source address and the LDS read address -> bank-conflict-free ds_read_b128
// with bit-identical per-lane fragments.
#define GLOAD_LDS16(gp, lp)                                                   \
    __builtin_amdgcn_global_load_lds(                                         \
        (const __attribute__((address_space(1))) void*)(gp),                  \
        (__attribute__((address_space(3))) void*)(lp), 16, 0, 0)

__global__ __launch_bounds__(256, 3) void gemm_gates_kernel(
    const short* __restrict__ agg, const float* __restrict__ hx,
    const short* __restrict__ Wbf,
    const float* __restrict__ bi, const float* __restrict__ bh,
    float* __restrict__ out, int N) {
    __shared__ short wlds[2][12288];            // 2 x 24.6 KB double buffer
    const int tid = threadIdx.x;
    const int wv = tid >> 6, lane = tid & 63;
    const int l15 = lane & 15, quad = lane >> 4;
    const int rowBase = (blockIdx.x * 4 + wv) * 16;
    // N is a multiple of 16, so an active wave always has 16 valid rows.
    // Inactive waves (tail block) must still stage + hit barriers.
    const bool active = rowBase < N;

    // A-fragments preloaded to registers BEFORE any out store (agg aliases
    // out; each wave reads/writes only its own 16 rows -> no hazard).
    int arow = active ? rowBase + l15 : 0;
    const short* aPtr = agg + (size_t)arow * 256;
    bf16x8 aLo[4], aHi[4];
    #pragma unroll
    for (int kst = 0; kst < 4; ++kst) {
        aLo[kst] = *(const bf16x8*)&aPtr[kst * 32 + quad * 8];
        aHi[kst] = *(const bf16x8*)&aPtr[128 + kst * 32 + quad * 8];
    }

    // Prologue: stage cb=0 slab (each wave copies its own 6144 B chunk).
    {
        const char* gs = (const char*)Wbf;
        #pragma unroll
        for (int i = 0; i < 6; ++i) {
            int ldsByte = wv * 6144 + i * 1024 + lane * 16;
            int gByte = ldsByte ^ (((ldsByte >> 8) & 15) << 4);   // slot ^= row&15
            GLOAD_LDS16(gs + gByte, (char*)&wlds[0][0] + wv * 6144 + i * 1024);
        }
    }
    __syncthreads();   // compiler drains vmcnt(0) before s_barrier

    for (int cb = 0; cb < 8; ++cb) {
        const int buf = cb & 1;
        if (cb < 7) {   // async prefetch next slab into the other buffer
            const char* gs = (const char*)(Wbf + (size_t)(cb + 1) * 12288);
            #pragma unroll
            for (int i = 0; i < 6; ++i) {
                int ldsByte = wv * 6144 + i * 1024 + lane * 16;
                int gByte = ldsByte ^ (((ldsByte >> 8) & 15) << 4);
                GLOAD_LDS16(gs + gByte,
                            (char*)&wlds[buf ^ 1][0] + wv * 6144 + i * 1024);
            }
        }
        if (active) {
            f32x4v acc[6];
            #pragma unroll
            for (int g = 0; g < 6; ++g) acc[g] = (f32x4v){0.f, 0.f, 0.f, 0.f};
            const char* slab = (const char*)&wlds[buf][0];
            #pragma unroll
            for (int kst = 0; kst < 4; ++kst) {
                const int co = (((kst * 4 + quad) ^ l15) << 4);   // swizzled col
                #pragma unroll
                for (int g = 0; g < 3; ++g) {
                    bf16x8 bI = *(const bf16x8*)(slab + g * 4096 + l15 * 256 + co);
                    acc[g] = __builtin_amdgcn_mfma_f32_16x16x32_bf16(
                        aLo[kst], bI, acc[g], 0, 0, 0);
                    bf16x8 bH = *(const bf16x8*)(slab + (g + 3) * 4096 + l15 * 256 + co);
                    acc[g + 3] = __builtin_amdgcn_mfma_f32_16x16x32_bf16(
                        aHi[kst], bH, acc[g + 3], 0, 0, 0);
                }
            }
            int ocol = cb * 16 + l15;
            float bir = bi[ocol], biz = bi[128 + ocol], bin = bi[256 + ocol];
            float bhr = bh[ocol], bhz = bh[128 + ocol], bhn = bh[256 + ocol];
            #pragma unroll
            for (int reg = 0; reg < 4; ++reg) {
                int row = rowBase + quad * 4 + reg;
                float ir = acc[0][reg] + bir, iz = acc[1][reg] + biz, in_ = acc[2][reg] + bin;
                float hr = acc[3][reg] + bhr, hz = acc[4][reg] + bhz, hn = acc[5][reg] + bhn;
                float rg = 1.0f / (1.0f + __expf(-(ir + hr)));
                float zg = 1.0f / (1.0f + __expf(-(iz + hz)));
                float ng = tanhf(in_ + rg * hn);
                float hv = hx[(size_t)row * DIM + ocol];
                out[(size_t)row * DIM + ocol] = (1.0f - zg) * ng + zg * hv;
            }
        }
        __syncthreads();   // drains this iter's prefetch; protects buf reuse
    }
}

// ---------------------------------------------------------------------------
extern "C" void kernel_launch(void* const* d_in, const int* in_sizes, int n_in,
                              void* d_out, int out_size, void* d_ws, size_t ws_size,
                              hipStream_t stream) {
    const float* feat = (const float*)d_in[0];
    const float* hx   = (const float*)d_in[1];
    const float* Wi   = (const float*)d_in[2];
    const float* bi   = (const float*)d_in[3];
    const float* Wh   = (const float*)d_in[4];
    const float* bh   = (const float*)d_in[5];
    const int* src    = (const int*)d_in[6];
    const int* dst    = (const int*)d_in[7];
    float* out        = (float*)d_out;

    int N = in_sizes[0] / DIM;   // 50000
    int E = in_sizes[6];         // 800000
    int NB = (N + 1023) / 1024;  // 49 (<=64 required by the wave scan)

    int* wsi = (int*)d_ws;
    int* degR      = wsi;                      // 8N (4 degO + 4 degI replicas)
    int* csrOff    = wsi + 8 * N;              // N+1
    int* cursor    = wsi + 9 * N + 1;          // N+1
    int* srcSorted = wsi + 10 * N + 2;         // E
    int* bsum      = wsi + 10 * N + 2 + E;     // 64
    float* normIf  = (float*)(bsum + 64);      // N
    size_t wofs = (((size_t)(11 * N + 2 + E + 64)) * 4 + 15) & ~(size_t)15;
    short* Wbf = (short*)((char*)d_ws + wofs);         // 98304 bf16
    size_t fofs = (wofs + 98304 * 2 + 15) & ~(size_t)15;
    short* fh = (short*)((char*)d_ws + fofs);          // N*256 bf16 (~25.6MB)
    // total ws: ~31.5 MB (proven-safe budget: 51.6 MB)
    short* agg = (short*)d_out;  // bf16 agg aliased over d_out

    hipMemsetAsync(degR, 0, (size_t)(8 * N) * sizeof(int), stream);
    k_deg<<<(E + 255) / 256, 256, 0, stream>>>(src, dst, degR, N, E);
    k_bsum<<<NB, 256, 0, stream>>>(degR, bsum, N);
    k_off<<<NB, 256, 0, stream>>>(degR, bsum, csrOff, cursor, N, NB);
    k_xcw<<<(N * 65 + 98304 + 255) / 256, 256, 0, stream>>>(
        feat, hx, Wi, Wh, degR, normIf, Wbf, fh, N);
    k_fill<<<(E + 255) / 256, 256, 0, stream>>>(src, dst, cursor, srcSorted, E);

    gather_kernel<<<(N + 3) / 4, 256, 0, stream>>>(
        fh, csrOff, srcSorted, normIf, agg, N);
    gemm_gates_kernel<<<(N + 63) / 64, 256, 0, stream>>>(
        agg, hx, Wbf, bi, bh, out, N);
}

// Round 4
// 306.724 us; speedup vs baseline: 1.1028x; 1.0769x over previous
//
#include <hip/hip_runtime.h>
#include <math.h>

#define DIM 128

typedef float f32x4v __attribute__((ext_vector_type(4)));
typedef short bf16x8 __attribute__((ext_vector_type(8)));

static __device__ __forceinline__ short f2bf(float f) {
    unsigned u = __float_as_uint(f);
    unsigned r = (u + 0x7fffu + ((u >> 16) & 1u)) >> 16;   // RNE
    return (short)r;
}
static __device__ __forceinline__ float bf2f(unsigned short s) {
    return __uint_as_float(((unsigned)s) << 16);
}

// ---------------------------------------------------------------------------
// K1: degree histogram with 4-way replicated counters. NEW: the degI
// atomicAdd's return value is captured as the edge's rank within its
// (replica, dst) group -> k_fill no longer needs any atomics.
__global__ __launch_bounds__(256) void k_deg(const int* __restrict__ src,
                                             const int* __restrict__ dst,
                                             int* degR, int* __restrict__ rank,
                                             int N, int E) {
    int e = blockIdx.x * 256 + threadIdx.x;
    if (e < E) {
        int r = threadIdx.x & 3;               // == e & 3 (reproduced in fill)
        atomicAdd(&degR[r * N + src[e]], 1);
        rank[e] = atomicAdd(&degR[(4 + r) * N + dst[e]], 1);
    }
}

// K2: per-1024-chunk sums of degI (over replicas).
__global__ __launch_bounds__(256) void k_bsum(const int* __restrict__ degR,
                                              int* __restrict__ bsum, int N) {
    __shared__ int red[4];
    int b = blockIdx.x, t = threadIdx.x;
    int idx = b * 1024 + t * 4;
    int s = 0;
    #pragma unroll
    for (int r = 4; r < 8; ++r) {
        const int* dI = degR + r * N;
        for (int j = 0; j < 4; ++j) if (idx + j < N) s += dI[idx + j];
    }
    for (int off = 32; off; off >>= 1) s += __shfl_down(s, off);
    if ((t & 63) == 0) red[t >> 6] = s;
    __syncthreads();
    if (t == 0) bsum[b] = red[0] + red[1] + red[2] + red[3];
}

// K3: per-chunk exclusive scan -> csrOff + per-replica bases csrOffR.
// csrOffR[r*N+d] = csrOff[d] + sum of replica counts r' < r for node d.
__global__ __launch_bounds__(256) void k_off(const int* __restrict__ degR,
                                             const int* __restrict__ bsum,
                                             int* __restrict__ csrOff,
                                             int* __restrict__ csrOffR,
                                             int N, int NB) {
    __shared__ int sp[256];
    __shared__ int sbase;
    int b = blockIdx.x, t = threadIdx.x;
    if (t < 64) {
        int own = (t < NB) ? bsum[t] : 0;
        int v = own;
        for (int off = 1; off < 64; off <<= 1) {
            int u = __shfl_up(v, off);
            if (t >= off) v += u;
        }
        if (t == b) sbase = v - own;
        if (b == 0 && t == NB - 1) csrOff[N] = v;
    }
    __syncthreads();
    int idx = b * 1024 + t * 4;
    int c[4][4];                               // [j][replica]
    #pragma unroll
    for (int r = 0; r < 4; ++r) {
        const int* dI = degR + (4 + r) * N;
        #pragma unroll
        for (int j = 0; j < 4; ++j) c[j][r] = (idx + j < N) ? dI[idx + j] : 0;
    }
    int va[4];
    #pragma unroll
    for (int j = 0; j < 4; ++j) va[j] = c[j][0] + c[j][1] + c[j][2] + c[j][3];
    int s = va[0] + va[1] + va[2] + va[3];
    sp[t] = s;
    __syncthreads();
    for (int off = 1; off < 256; off <<= 1) {
        int u = (t >= off) ? sp[t - off] : 0;
        __syncthreads();
        sp[t] += u;
        __syncthreads();
    }
    int o = sbase + sp[t] - s;
    #pragma unroll
    for (int j = 0; j < 4; ++j) {
        if (idx + j < N) {
            csrOff[idx + j] = o;
            int base = o;
            #pragma unroll
            for (int r = 0; r < 4; ++r) {
                csrOffR[r * N + idx + j] = base;
                base += c[j][r];
            }
        }
        o += va[j];
    }
}

// K4: merged normI + pre-scaled bf16 feat/hx + bf16 weight convert +
// NEW: atomic-free counting-sort fill (pos = csrOffR[replica][dst] + rank).
__global__ __launch_bounds__(256) void k_xcw(const float* __restrict__ feat,
                                             const float* __restrict__ hx,
                                             const float* __restrict__ Wi,
                                             const float* __restrict__ Wh,
                                             const int* __restrict__ degR,
                                             float* __restrict__ normIf,
                                             short* __restrict__ Wbf,
                                             short* __restrict__ fh,
                                             const int* __restrict__ src,
                                             const int* __restrict__ dst,
                                             const int* __restrict__ rank,
                                             const int* __restrict__ csrOffR,
                                             int* __restrict__ srcSorted,
                                             int N, int E) {
    int i = blockIdx.x * 256 + threadIdx.x;
    int T1 = N * 64, T2 = N * 64 + N;
    int T3 = T2 + 98304;
    if (i < T1) {
        int n = i >> 6, q = i & 63;
        int dO = degR[n] + degR[N + n] + degR[2 * N + n] + degR[3 * N + n];
        float ns = rsqrtf(fmaxf((float)dO, 1.0f));
        const float* spp = (q < 32) ? &feat[(size_t)n * 128 + q * 4]
                                    : &hx[(size_t)n * 128 + (q - 32) * 4];
        float4 v = *(const float4*)spp;
        short4 p;
        p.x = f2bf(v.x * ns); p.y = f2bf(v.y * ns);
        p.z = f2bf(v.z * ns); p.w = f2bf(v.w * ns);
        *(short4*)&fh[(size_t)n * 256 + q * 4] = p;   // q*4 == 128+(q-32)*4
    } else if (i < T2) {
        int n = i - T1;
        int dI = degR[4 * N + n] + degR[5 * N + n] + degR[6 * N + n] + degR[7 * N + n];
        normIf[n] = rsqrtf(fmaxf((float)dI, 1.0f));
    } else if (i < T3) {
        int w = i - T2;
        int k = w & 127, n = (w >> 7) & 15, r = w >> 11;
        int gm = r % 6, cb = r / 6;
        const float* Wsrc = (gm < 3) ? Wi : Wh;
        int g = gm % 3;
        Wbf[w] = f2bf(Wsrc[k * 384 + g * 128 + cb * 16 + n]);
    } else {
        int e = i - T3;
        if (e < E) {
            int r = e & 3;                      // matches k_deg's tid&3
            int pos = csrOffR[r * N + dst[e]] + rank[e];
            srcSorted[pos] = src[e];
        }
    }
}

// ---------------------------------------------------------------------------
// K6: gather-aggregate. One wave per dst node, no LDS, 8 B/lane row reads,
// wave-uniform scalar index loads (R1 structure, 28-VGPR class — proven
// best across R1/R2/R3; the compiler pins MLP regardless of source order).
__global__ __launch_bounds__(256) void gather_kernel(
    const short* __restrict__ fh, const int* __restrict__ csrOff,
    const int* __restrict__ srcSorted, const float* __restrict__ normIf,
    short* __restrict__ agg, int N) {
    int wv = threadIdx.x >> 6, lane = threadIdx.x & 63;
    int d = blockIdx.x * 4 + wv;
    if (d >= N) return;
    const ushort4* fh4 = (const ushort4*)fh;
    int beg = csrOff[d], end = csrOff[d + 1];
    float4 acc = make_float4(0.f, 0.f, 0.f, 0.f);
    #pragma unroll 8
    for (int e = beg; e < end; ++e) {
        int s = srcSorted[e];                     // wave-uniform scalar load
        ushort4 v = fh4[(size_t)s * 64 + lane];   // 8B/lane, 512B/wave
        acc.x += bf2f(v.x); acc.y += bf2f(v.y);
        acc.z += bf2f(v.z); acc.w += bf2f(v.w);
    }
    float nd = normIf[d];
    short4 p;
    p.x = f2bf(acc.x * nd); p.y = f2bf(acc.y * nd);
    p.z = f2bf(acc.z * nd); p.w = f2bf(acc.w * nd);
    *(short4*)&agg[(size_t)d * 256 + lane * 4] = p;
}

// ---------------------------------------------------------------------------
// K7: dense bf16 MFMA GEMM + GRU gates. Weights staged per-cb into LDS via
// global_load_lds (width=16), double-buffered, shared by the 4 waves of the
// block. LDS layout XOR-swizzled (16B slot ^= row&15) on BOTH the global
// source address and the LDS read address -> bank-conflict-free ds_read_b128
// with bit-identical per-lane fragments.
#define GLOAD_LDS16(gp, lp)                                                   \
    __builtin_amdgcn_global_load_lds(                                         \
        (const __attribute__((address_space(1))) void*)(gp),                  \
        (__attribute__((address_space(3))) void*)(lp), 16, 0, 0)

__global__ __launch_bounds__(256, 3) void gemm_gates_kernel(
    const short* __restrict__ agg, const float* __restrict__ hx,
    const short* __restrict__ Wbf,
    const float* __restrict__ bi, const float* __restrict__ bh,
    float* __restrict__ out, int N) {
    __shared__ short wlds[2][12288];            // 2 x 24.6 KB double buffer
    const int tid = threadIdx.x;
    const int wv = tid >> 6, lane = tid & 63;
    const int l15 = lane & 15, quad = lane >> 4;
    const int rowBase = (blockIdx.x * 4 + wv) * 16;
    // N is a multiple of 16, so an active wave always has 16 valid rows.
    // Inactive waves (tail block) must still stage + hit barriers.
    const bool active = rowBase < N;

    // A-fragments preloaded to registers BEFORE any out store (agg aliases
    // out; each wave reads/writes only its own 16 rows -> no hazard).
    int arow = active ? rowBase + l15 : 0;
    const short* aPtr = agg + (size_t)arow * 256;
    bf16x8 aLo[4], aHi[4];
    #pragma unroll
    for (int kst = 0; kst < 4; ++kst) {
        aLo[kst] = *(const bf16x8*)&aPtr[kst * 32 + quad * 8];
        aHi[kst] = *(const bf16x8*)&aPtr[128 + kst * 32 + quad * 8];
    }

    // Prologue: stage cb=0 slab (each wave copies its own 6144 B chunk).
    {
        const char* gs = (const char*)Wbf;
        #pragma unroll
        for (int i = 0; i < 6; ++i) {
            int ldsByte = wv * 6144 + i * 1024 + lane * 16;
            int gByte = ldsByte ^ (((ldsByte >> 8) & 15) << 4);   // slot ^= row&15
            GLOAD_LDS16(gs + gByte, (char*)&wlds[0][0] + wv * 6144 + i * 1024);
        }
    }
    __syncthreads();   // compiler drains vmcnt(0) before s_barrier

    for (int cb = 0; cb < 8; ++cb) {
        const int buf = cb & 1;
        if (cb < 7) {   // async prefetch next slab into the other buffer
            const char* gs = (const char*)(Wbf + (size_t)(cb + 1) * 12288);
            #pragma unroll
            for (int i = 0; i < 6; ++i) {
                int ldsByte = wv * 6144 + i * 1024 + lane * 16;
                int gByte = ldsByte ^ (((ldsByte >> 8) & 15) << 4);
                GLOAD_LDS16(gs + gByte,
                            (char*)&wlds[buf ^ 1][0] + wv * 6144 + i * 1024);
            }
        }
        if (active) {
            f32x4v acc[6];
            #pragma unroll
            for (int g = 0; g < 6; ++g) acc[g] = (f32x4v){0.f, 0.f, 0.f, 0.f};
            const char* slab = (const char*)&wlds[buf][0];
            #pragma unroll
            for (int kst = 0; kst < 4; ++kst) {
                const int co = (((kst * 4 + quad) ^ l15) << 4);   // swizzled col
                #pragma unroll
                for (int g = 0; g < 3; ++g) {
                    bf16x8 bI = *(const bf16x8*)(slab + g * 4096 + l15 * 256 + co);
                    acc[g] = __builtin_amdgcn_mfma_f32_16x16x32_bf16(
                        aLo[kst], bI, acc[g], 0, 0, 0);
                    bf16x8 bH = *(const bf16x8*)(slab + (g + 3) * 4096 + l15 * 256 + co);
                    acc[g + 3] = __builtin_amdgcn_mfma_f32_16x16x32_bf16(
                        aHi[kst], bH, acc[g + 3], 0, 0, 0);
                }
            }
            int ocol = cb * 16 + l15;
            float bir = bi[ocol], biz = bi[128 + ocol], bin = bi[256 + ocol];
            float bhr = bh[ocol], bhz = bh[128 + ocol], bhn = bh[256 + ocol];
            #pragma unroll
            for (int reg = 0; reg < 4; ++reg) {
                int row = rowBase + quad * 4 + reg;
                float ir = acc[0][reg] + bir, iz = acc[1][reg] + biz, in_ = acc[2][reg] + bin;
                float hr = acc[3][reg] + bhr, hz = acc[4][reg] + bhz, hn = acc[5][reg] + bhn;
                float rg = 1.0f / (1.0f + __expf(-(ir + hr)));
                float zg = 1.0f / (1.0f + __expf(-(iz + hz)));
                float ng = tanhf(in_ + rg * hn);
                float hv = hx[(size_t)row * DIM + ocol];
                out[(size_t)row * DIM + ocol] = (1.0f - zg) * ng + zg * hv;
            }
        }
        __syncthreads();   // drains this iter's prefetch; protects buf reuse
    }
}

// ---------------------------------------------------------------------------
extern "C" void kernel_launch(void* const* d_in, const int* in_sizes, int n_in,
                              void* d_out, int out_size, void* d_ws, size_t ws_size,
                              hipStream_t stream) {
    const float* feat = (const float*)d_in[0];
    const float* hx   = (const float*)d_in[1];
    const float* Wi   = (const float*)d_in[2];
    const float* bi   = (const float*)d_in[3];
    const float* Wh   = (const float*)d_in[4];
    const float* bh   = (const float*)d_in[5];
    const int* src    = (const int*)d_in[6];
    const int* dst    = (const int*)d_in[7];
    float* out        = (float*)d_out;

    int N = in_sizes[0] / DIM;   // 50000
    int E = in_sizes[6];         // 800000
    int NB = (N + 1023) / 1024;  // 49 (<=64 required by the wave scan)

    int* wsi = (int*)d_ws;
    int* degR      = wsi;                      // 8N (4 degO + 4 degI replicas)
    int* csrOff    = wsi + 8 * N;              // N+1
    int* csrOffR   = wsi + 9 * N + 1;          // 4N (per-replica bases)
    int* srcSorted = wsi + 13 * N + 1;         // E
    int* rank      = wsi + 13 * N + 1 + E;     // E
    int* bsum      = wsi + 13 * N + 1 + 2 * E; // 64
    float* normIf  = (float*)(bsum + 64);      // N
    size_t wofs = (((size_t)(14 * N + 1 + 2 * E + 64)) * 4 + 15) & ~(size_t)15;
    short* Wbf = (short*)((char*)d_ws + wofs);         // 98304 bf16
    size_t fofs = (wofs + 98304 * 2 + 15) & ~(size_t)15;
    short* fh = (short*)((char*)d_ws + fofs);          // N*256 bf16 (~25.6MB)
    // total ws: ~35 MB (proven-safe budget: 51.6 MB)
    short* agg = (short*)d_out;  // bf16 agg aliased over d_out

    hipMemsetAsync(degR, 0, (size_t)(8 * N) * sizeof(int), stream);
    k_deg<<<(E + 255) / 256, 256, 0, stream>>>(src, dst, degR, rank, N, E);
    k_bsum<<<NB, 256, 0, stream>>>(degR, bsum, N);
    k_off<<<NB, 256, 0, stream>>>(degR, bsum, csrOff, csrOffR, N, NB);
    k_xcw<<<(N * 65 + 98304 + E + 255) / 256, 256, 0, stream>>>(
        feat, hx, Wi, Wh, degR, normIf, Wbf, fh,
        src, dst, rank, csrOffR, srcSorted, N, E);

    gather_kernel<<<(N + 3) / 4, 256, 0, stream>>>(
        fh, csrOff, srcSorted, normIf, agg, N);
    gemm_gates_kernel<<<(N + 63) / 64, 256, 0, stream>>>(
        agg, hx, Wbf, bi, bh, out, N);
}

// Round 5
// 306.177 us; speedup vs baseline: 1.1048x; 1.0018x over previous
//
#include <hip/hip_runtime.h>
#include <math.h>

#define DIM 128

typedef float f32x4v __attribute__((ext_vector_type(4)));
typedef short bf16x8 __attribute__((ext_vector_type(8)));

static __device__ __forceinline__ short f2bf(float f) {
    unsigned u = __float_as_uint(f);
    unsigned r = (u + 0x7fffu + ((u >> 16) & 1u)) >> 16;   // RNE
    return (short)r;
}
static __device__ __forceinline__ float bf2f(unsigned short s) {
    return __uint_as_float(((unsigned)s) << 16);
}

// ---------------------------------------------------------------------------
// K1: degree histogram in PER-XCD tables with XCD-LOCAL (L2-resolved) atomics.
// R4's profile: device-scope atomics write-through to the fabric (53 MB HBM
// writes for a 1.6 MB table, 84 us). A workgroup never migrates XCDs and all
// global atomics from one XCD serialize in that XCD's TCC, so WORKGROUP-scope
// relaxed atomics on a per-XCD table are correct and resolve in local L2.
// Cross-kernel visibility comes from the dispatch-boundary L2 writeback.
// degX layout: [xcd][2][N] -> degO at xcd*2N + n, degI at xcd*2N + N + n.
// rank packs (xcd<<24)|local_rank; local_rank < E < 2^24.
__global__ __launch_bounds__(256) void k_deg(const int* __restrict__ src,
                                             const int* __restrict__ dst,
                                             int* degX, int* __restrict__ rank,
                                             int N, int E) {
    int xcd;
    asm volatile("s_getreg_b32 %0, hwreg(HW_REG_XCC_ID)" : "=s"(xcd));
    xcd &= 7;
    int e = blockIdx.x * 256 + threadIdx.x;
    if (e < E) {
        int* b = degX + (size_t)xcd * 2 * N;
        __hip_atomic_fetch_add(&b[src[e]], 1, __ATOMIC_RELAXED,
                               __HIP_MEMORY_SCOPE_WORKGROUP);
        int r = __hip_atomic_fetch_add(&b[N + dst[e]], 1, __ATOMIC_RELAXED,
                                       __HIP_MEMORY_SCOPE_WORKGROUP);
        rank[e] = (xcd << 24) | r;
    }
}

// K2: per-1024-chunk sums of degI (over the 8 XCD tables).
__global__ __launch_bounds__(256) void k_bsum(const int* __restrict__ degX,
                                              int* __restrict__ bsum, int N) {
    __shared__ int red[4];
    int b = blockIdx.x, t = threadIdx.x;
    int idx = b * 1024 + t * 4;
    int s = 0;
    #pragma unroll
    for (int x = 0; x < 8; ++x) {
        const int* dI = degX + (size_t)x * 2 * N + N;
        for (int j = 0; j < 4; ++j) if (idx + j < N) s += dI[idx + j];
    }
    for (int off = 32; off; off >>= 1) s += __shfl_down(s, off);
    if ((t & 63) == 0) red[t >> 6] = s;
    __syncthreads();
    if (t == 0) bsum[b] = red[0] + red[1] + red[2] + red[3];
}

// K3: per-chunk exclusive scan -> csrOff + per-XCD bases csrOffX.
// csrOffX[x*N+d] = csrOff[d] + sum of degI from XCDs x' < x for node d.
__global__ __launch_bounds__(256) void k_off(const int* __restrict__ degX,
                                             const int* __restrict__ bsum,
                                             int* __restrict__ csrOff,
                                             int* __restrict__ csrOffX,
                                             int N, int NB) {
    __shared__ int sp[256];
    __shared__ int sbase;
    int b = blockIdx.x, t = threadIdx.x;
    if (t < 64) {
        int own = (t < NB) ? bsum[t] : 0;
        int v = own;
        for (int off = 1; off < 64; off <<= 1) {
            int u = __shfl_up(v, off);
            if (t >= off) v += u;
        }
        if (t == b) sbase = v - own;
        if (b == 0 && t == NB - 1) csrOff[N] = v;
    }
    __syncthreads();
    int idx = b * 1024 + t * 4;
    int c[4][8];                               // [j][xcd]
    #pragma unroll
    for (int x = 0; x < 8; ++x) {
        const int* dI = degX + (size_t)x * 2 * N + N;
        #pragma unroll
        for (int j = 0; j < 4; ++j) c[j][x] = (idx + j < N) ? dI[idx + j] : 0;
    }
    int va[4];
    #pragma unroll
    for (int j = 0; j < 4; ++j) {
        int a = 0;
        #pragma unroll
        for (int x = 0; x < 8; ++x) a += c[j][x];
        va[j] = a;
    }
    int s = va[0] + va[1] + va[2] + va[3];
    sp[t] = s;
    __syncthreads();
    for (int off = 1; off < 256; off <<= 1) {
        int u = (t >= off) ? sp[t - off] : 0;
        __syncthreads();
        sp[t] += u;
        __syncthreads();
    }
    int o = sbase + sp[t] - s;
    #pragma unroll
    for (int j = 0; j < 4; ++j) {
        if (idx + j < N) {
            csrOff[idx + j] = o;
            int base = o;
            #pragma unroll
            for (int x = 0; x < 8; ++x) {
                csrOffX[(size_t)x * N + idx + j] = base;
                base += c[j][x];
            }
        }
        o += va[j];
    }
}

// K4: merged normI + pre-scaled bf16 feat/hx + bf16 weight convert +
// atomic-free counting-sort fill (pos = csrOffX[xcd][dst] + rank).
__global__ __launch_bounds__(256) void k_xcw(const float* __restrict__ feat,
                                             const float* __restrict__ hx,
                                             const float* __restrict__ Wi,
                                             const float* __restrict__ Wh,
                                             const int* __restrict__ degX,
                                             float* __restrict__ normIf,
                                             short* __restrict__ Wbf,
                                             short* __restrict__ fh,
                                             const int* __restrict__ src,
                                             const int* __restrict__ dst,
                                             const int* __restrict__ rank,
                                             const int* __restrict__ csrOffX,
                                             int* __restrict__ srcSorted,
                                             int N, int E) {
    int i = blockIdx.x * 256 + threadIdx.x;
    int T1 = N * 64, T2 = N * 64 + N;
    int T3 = T2 + 98304;
    if (i < T1) {
        int n = i >> 6, q = i & 63;
        int dO = 0;
        #pragma unroll
        for (int x = 0; x < 8; ++x) dO += degX[(size_t)x * 2 * N + n];
        float ns = rsqrtf(fmaxf((float)dO, 1.0f));
        const float* spp = (q < 32) ? &feat[(size_t)n * 128 + q * 4]
                                    : &hx[(size_t)n * 128 + (q - 32) * 4];
        float4 v = *(const float4*)spp;
        short4 p;
        p.x = f2bf(v.x * ns); p.y = f2bf(v.y * ns);
        p.z = f2bf(v.z * ns); p.w = f2bf(v.w * ns);
        *(short4*)&fh[(size_t)n * 256 + q * 4] = p;   // q*4 == 128+(q-32)*4
    } else if (i < T2) {
        int n = i - T1;
        int dI = 0;
        #pragma unroll
        for (int x = 0; x < 8; ++x) dI += degX[(size_t)x * 2 * N + N + n];
        normIf[n] = rsqrtf(fmaxf((float)dI, 1.0f));
    } else if (i < T3) {
        int w = i - T2;
        int k = w & 127, n = (w >> 7) & 15, r = w >> 11;
        int gm = r % 6, cb = r / 6;
        const float* Wsrc = (gm < 3) ? Wi : Wh;
        int g = gm % 3;
        Wbf[w] = f2bf(Wsrc[k * 384 + g * 128 + cb * 16 + n]);
    } else {
        int e = i - T3;
        if (e < E) {
            int rr = rank[e];
            int x = rr >> 24, rk = rr & 0xFFFFFF;
            int pos = csrOffX[(size_t)x * N + dst[e]] + rk;
            srcSorted[pos] = src[e];
        }
    }
}

// ---------------------------------------------------------------------------
// K6: gather-aggregate. One wave per dst node, no LDS, 8 B/lane row reads,
// wave-uniform scalar index loads (R1 structure, 28-VGPR class — proven
// best across R1/R2/R3; the compiler pins MLP regardless of source order).
__global__ __launch_bounds__(256) void gather_kernel(
    const short* __restrict__ fh, const int* __restrict__ csrOff,
    const int* __restrict__ srcSorted, const float* __restrict__ normIf,
    short* __restrict__ agg, int N) {
    int wv = threadIdx.x >> 6, lane = threadIdx.x & 63;
    int d = blockIdx.x * 4 + wv;
    if (d >= N) return;
    const ushort4* fh4 = (const ushort4*)fh;
    int beg = csrOff[d], end = csrOff[d + 1];
    float4 acc = make_float4(0.f, 0.f, 0.f, 0.f);
    #pragma unroll 8
    for (int e = beg; e < end; ++e) {
        int s = srcSorted[e];                     // wave-uniform scalar load
        ushort4 v = fh4[(size_t)s * 64 + lane];   // 8B/lane, 512B/wave
        acc.x += bf2f(v.x); acc.y += bf2f(v.y);
        acc.z += bf2f(v.z); acc.w += bf2f(v.w);
    }
    float nd = normIf[d];
    short4 p;
    p.x = f2bf(acc.x * nd); p.y = f2bf(acc.y * nd);
    p.z = f2bf(acc.z * nd); p.w = f2bf(acc.w * nd);
    *(short4*)&agg[(size_t)d * 256 + lane * 4] = p;
}

// ---------------------------------------------------------------------------
// K7: dense bf16 MFMA GEMM + GRU gates. Weights staged per-cb into LDS via
// global_load_lds (width=16), double-buffered, shared by the 4 waves of the
// block. LDS layout XOR-swizzled (16B slot ^= row&15) on BOTH the global
// source address and the LDS read address -> bank-conflict-free ds_read_b128
// with bit-identical per-lane fragments.
#define GLOAD_LDS16(gp, lp)                                                   \
    __builtin_amdgcn_global_load_lds(                                         \
        (const __attribute__((address_space(1))) void*)(gp),                  \
        (__attribute__((address_space(3))) void*)(lp), 16, 0, 0)

__global__ __launch_bounds__(256, 3) void gemm_gates_kernel(
    const short* __restrict__ agg, const float* __restrict__ hx,
    const short* __restrict__ Wbf,
    const float* __restrict__ bi, const float* __restrict__ bh,
    float* __restrict__ out, int N) {
    __shared__ short wlds[2][12288];            // 2 x 24.6 KB double buffer
    const int tid = threadIdx.x;
    const int wv = tid >> 6, lane = tid & 63;
    const int l15 = lane & 15, quad = lane >> 4;
    const int rowBase = (blockIdx.x * 4 + wv) * 16;
    // N is a multiple of 16, so an active wave always has 16 valid rows.
    // Inactive waves (tail block) must still stage + hit barriers.
    const bool active = rowBase < N;

    // A-fragments preloaded to registers BEFORE any out store (agg aliases
    // out; each wave reads/writes only its own 16 rows -> no hazard).
    int arow = active ? rowBase + l15 : 0;
    const short* aPtr = agg + (size_t)arow * 256;
    bf16x8 aLo[4], aHi[4];
    #pragma unroll
    for (int kst = 0; kst < 4; ++kst) {
        aLo[kst] = *(const bf16x8*)&aPtr[kst * 32 + quad * 8];
        aHi[kst] = *(const bf16x8*)&aPtr[128 + kst * 32 + quad * 8];
    }

    // Prologue: stage cb=0 slab (each wave copies its own 6144 B chunk).
    {
        const char* gs = (const char*)Wbf;
        #pragma unroll
        for (int i = 0; i < 6; ++i) {
            int ldsByte = wv * 6144 + i * 1024 + lane * 16;
            int gByte = ldsByte ^ (((ldsByte >> 8) & 15) << 4);   // slot ^= row&15
            GLOAD_LDS16(gs + gByte, (char*)&wlds[0][0] + wv * 6144 + i * 1024);
        }
    }
    __syncthreads();   // compiler drains vmcnt(0) before s_barrier

    for (int cb = 0; cb < 8; ++cb) {
        const int buf = cb & 1;
        if (cb < 7) {   // async prefetch next slab into the other buffer
            const char* gs = (const char*)(Wbf + (size_t)(cb + 1) * 12288);
            #pragma unroll
            for (int i = 0; i < 6; ++i) {
                int ldsByte = wv * 6144 + i * 1024 + lane * 16;
                int gByte = ldsByte ^ (((ldsByte >> 8) & 15) << 4);
                GLOAD_LDS16(gs + gByte,
                            (char*)&wlds[buf ^ 1][0] + wv * 6144 + i * 1024);
            }
        }
        if (active) {
            f32x4v acc[6];
            #pragma unroll
            for (int g = 0; g < 6; ++g) acc[g] = (f32x4v){0.f, 0.f, 0.f, 0.f};
            const char* slab = (const char*)&wlds[buf][0];
            #pragma unroll
            for (int kst = 0; kst < 4; ++kst) {
                const int co = (((kst * 4 + quad) ^ l15) << 4);   // swizzled col
                #pragma unroll
                for (int g = 0; g < 3; ++g) {
                    bf16x8 bI = *(const bf16x8*)(slab + g * 4096 + l15 * 256 + co);
                    acc[g] = __builtin_amdgcn_mfma_f32_16x16x32_bf16(
                        aLo[kst], bI, acc[g], 0, 0, 0);
                    bf16x8 bH = *(const bf16x8*)(slab + (g + 3) * 4096 + l15 * 256 + co);
                    acc[g + 3] = __builtin_amdgcn_mfma_f32_16x16x32_bf16(
                        aHi[kst], bH, acc[g + 3], 0, 0, 0);
                }
            }
            int ocol = cb * 16 + l15;
            float bir = bi[ocol], biz = bi[128 + ocol], bin = bi[256 + ocol];
            float bhr = bh[ocol], bhz = bh[128 + ocol], bhn = bh[256 + ocol];
            #pragma unroll
            for (int reg = 0; reg < 4; ++reg) {
                int row = rowBase + quad * 4 + reg;
                float ir = acc[0][reg] + bir, iz = acc[1][reg] + biz, in_ = acc[2][reg] + bin;
                float hr = acc[3][reg] + bhr, hz = acc[4][reg] + bhz, hn = acc[5][reg] + bhn;
                float rg = 1.0f / (1.0f + __expf(-(ir + hr)));
                float zg = 1.0f / (1.0f + __expf(-(iz + hz)));
                float ng = tanhf(in_ + rg * hn);
                float hv = hx[(size_t)row * DIM + ocol];
                out[(size_t)row * DIM + ocol] = (1.0f - zg) * ng + zg * hv;
            }
        }
        __syncthreads();   // drains this iter's prefetch; protects buf reuse
    }
}

// ---------------------------------------------------------------------------
extern "C" void kernel_launch(void* const* d_in, const int* in_sizes, int n_in,
                              void* d_out, int out_size, void* d_ws, size_t ws_size,
                              hipStream_t stream) {
    const float* feat = (const float*)d_in[0];
    const float* hx   = (const float*)d_in[1];
    const float* Wi   = (const float*)d_in[2];
    const float* bi   = (const float*)d_in[3];
    const float* Wh   = (const float*)d_in[4];
    const float* bh   = (const float*)d_in[5];
    const int* src    = (const int*)d_in[6];
    const int* dst    = (const int*)d_in[7];
    float* out        = (float*)d_out;

    int N = in_sizes[0] / DIM;   // 50000
    int E = in_sizes[6];         // 800000
    int NB = (N + 1023) / 1024;  // 49 (<=64 required by the wave scan)

    int* wsi = (int*)d_ws;
    int* degX      = wsi;                       // 16N (8 XCDs x {degO,degI})
    int* csrOff    = wsi + 16 * N;              // N+1
    int* csrOffX   = wsi + 17 * N + 1;          // 8N (per-XCD bases)
    int* srcSorted = wsi + 25 * N + 1;          // E
    int* rank      = wsi + 25 * N + 1 + E;      // E (packed xcd<<24 | rank)
    int* bsum      = wsi + 25 * N + 1 + 2 * E;  // 64
    float* normIf  = (float*)(bsum + 64);       // N
    size_t wofs = (((size_t)(26 * N + 1 + 2 * E + 64)) * 4 + 15) & ~(size_t)15;
    short* Wbf = (short*)((char*)d_ws + wofs);         // 98304 bf16
    size_t fofs = (wofs + 98304 * 2 + 15) & ~(size_t)15;
    short* fh = (short*)((char*)d_ws + fofs);          // N*256 bf16 (~25.6MB)
    // total ws: ~37.5 MB (proven-safe budget: 51.6 MB)
    short* agg = (short*)d_out;  // bf16 agg aliased over d_out

    hipMemsetAsync(degX, 0, (size_t)(16 * N) * sizeof(int), stream);
    k_deg<<<(E + 255) / 256, 256, 0, stream>>>(src, dst, degX, rank, N, E);
    k_bsum<<<NB, 256, 0, stream>>>(degX, bsum, N);
    k_off<<<NB, 256, 0, stream>>>(degX, bsum, csrOff, csrOffX, N, NB);
    k_xcw<<<(N * 65 + 98304 + E + 255) / 256, 256, 0, stream>>>(
        feat, hx, Wi, Wh, degX, normIf, Wbf, fh,
        src, dst, rank, csrOffX, srcSorted, N, E);

    gather_kernel<<<(N + 3) / 4, 256, 0, stream>>>(
        fh, csrOff, srcSorted, normIf, agg, N);
    gemm_gates_kernel<<<(N + 63) / 64, 256, 0, stream>>>(
        agg, hx, Wbf, bi, bh, out, N);
}

// Round 6
// 276.032 us; speedup vs baseline: 1.2254x; 1.1092x over previous
//
#include <hip/hip_runtime.h>
#include <math.h>

#define DIM 128
#define NCH 32          // edge chunks (partial-histogram count)
#define RGMAX 6272      // max nodes per LDS range (2*RGMAX*4 = 50 KB LDS)

typedef float f32x4v __attribute__((ext_vector_type(4)));
typedef short bf16x8 __attribute__((ext_vector_type(8)));

static __device__ __forceinline__ short f2bf(float f) {
    unsigned u = __float_as_uint(f);
    unsigned r = (u + 0x7fffu + ((u >> 16) & 1u)) >> 16;   // RNE
    return (short)r;
}
static __device__ __forceinline__ float bf2f(unsigned short s) {
    return __uint_as_float(((unsigned)s) << 16);
}

// ---------------------------------------------------------------------------
// K1: LDS-histogram degree count, NO global atomics. R4/R5 proved gfx950
// global atomics write through to the memory-side coherence point at a fixed
// ~53 ns/KB cost (84 us for 1.6M atomics) regardless of table replication or
// source-level scope. Fix: (chunk x range) grid; block (c,r) streams edge
// chunk c and counts src/dst keys falling in node range r into LDS with
// ds_add_rtn (CU-local). The returned old value IS the intra-(chunk,dst)
// rank -> counting sort still works. Partials go to partO/partI[c][n].
__global__ __launch_bounds__(256) void k_hist(const int* __restrict__ src,
                                              const int* __restrict__ dst,
                                              int* __restrict__ partO,
                                              int* __restrict__ partI,
                                              int* __restrict__ rank,
                                              int N, int E, int chunk, int rgsz) {
    __shared__ int hO[RGMAX], hI[RGMAX];
    int t = threadIdx.x;
    int c = blockIdx.x % NCH, r = blockIdx.x / NCH;
    int lo = r * rgsz;
    int hi = min(lo + rgsz, N);
    for (int i = t; i < rgsz; i += 256) { hO[i] = 0; hI[i] = 0; }
    __syncthreads();
    int e0 = c * chunk, e1 = min(e0 + chunk, E);
    for (int e = e0 + t; e < e1; e += 256) {
        int s = src[e], d = dst[e];
        if (s >= lo && s < hi) atomicAdd(&hO[s - lo], 1);          // LDS atomic
        if (d >= lo && d < hi) rank[e] = atomicAdd(&hI[d - lo], 1);
    }
    __syncthreads();
    for (int i = t; i < hi - lo; i += 256) {
        partO[(size_t)c * N + lo + i] = hO[i];
        partI[(size_t)c * N + lo + i] = hI[i];
    }
}

// K2: per-256-node block sums of degI (over the NCH chunk partials).
__global__ __launch_bounds__(256) void k_bsum(const int* __restrict__ partI,
                                              int* __restrict__ bsum, int N) {
    __shared__ int red[4];
    int b = blockIdx.x, t = threadIdx.x;
    int n = b * 256 + t;
    int s = 0;
    if (n < N) {
        #pragma unroll
        for (int c = 0; c < NCH; ++c) s += partI[(size_t)c * N + n];
    }
    for (int off = 32; off; off >>= 1) s += __shfl_down(s, off);
    if ((t & 63) == 0) red[t >> 6] = s;
    __syncthreads();
    if (t == 0) bsum[b] = red[0] + red[1] + red[2] + red[3];
}

// K3: exclusive scan -> csrOff + per-chunk bases csrOffC + norm factors.
// One node per thread, NB <= 256 blocks, LDS Hillis-Steele scans.
// csrOffC ALIASES partO (same pointer): each thread reads its partO entries
// before overwriting the same addresses -> safe (thread-private indices).
__global__ __launch_bounds__(256) void k_off(const int* __restrict__ partI,
                                             int* partO_csrC,   // in: partO, out: csrOffC
                                             const int* __restrict__ bsum,
                                             int* __restrict__ csrOff,
                                             float* __restrict__ normIf,
                                             float* __restrict__ normOf,
                                             int N, int NB) {
    __shared__ int sp[256];
    __shared__ int sbase;
    int b = blockIdx.x, t = threadIdx.x;
    int own = (t < NB) ? bsum[t] : 0;
    sp[t] = own;
    __syncthreads();
    for (int off = 1; off < 256; off <<= 1) {
        int u = (t >= off) ? sp[t - off] : 0;
        __syncthreads();
        sp[t] += u;
        __syncthreads();
    }
    if (t == b) sbase = sp[t] - own;
    if (b == 0 && t == NB - 1) csrOff[N] = sp[t];
    __syncthreads();
    int n = b * 256 + t;
    int cv[NCH];
    int tI = 0, tO = 0;
    if (n < N) {
        #pragma unroll
        for (int c = 0; c < NCH; ++c) {
            cv[c] = partI[(size_t)c * N + n];
            tI += cv[c];
            tO += partO_csrC[(size_t)c * N + n];
        }
    }
    sp[t] = tI;
    __syncthreads();
    for (int off = 1; off < 256; off <<= 1) {
        int u = (t >= off) ? sp[t - off] : 0;
        __syncthreads();
        sp[t] += u;
        __syncthreads();
    }
    int o = sbase + sp[t] - tI;
    if (n < N) {
        csrOff[n] = o;
        normIf[n] = rsqrtf(fmaxf((float)tI, 1.0f));
        normOf[n] = rsqrtf(fmaxf((float)tO, 1.0f));
        int base = o;
        #pragma unroll
        for (int c = 0; c < NCH; ++c) {
            partO_csrC[(size_t)c * N + n] = base;   // csrOffC[c][n]
            base += cv[c];
        }
    }
}

// K4: merged pre-scaled bf16 feat/hx + bf16 weight convert + atomic-free
// counting-sort fill (pos = csrOffC[e/chunk][dst] + rank).
__global__ __launch_bounds__(256) void k_xcw(const float* __restrict__ feat,
                                             const float* __restrict__ hx,
                                             const float* __restrict__ Wi,
                                             const float* __restrict__ Wh,
                                             const float* __restrict__ normOf,
                                             short* __restrict__ Wbf,
                                             short* __restrict__ fh,
                                             const int* __restrict__ src,
                                             const int* __restrict__ dst,
                                             const int* __restrict__ rank,
                                             const int* __restrict__ csrOffC,
                                             int* __restrict__ srcSorted,
                                             int N, int E, int chunk) {
    int i = blockIdx.x * 256 + threadIdx.x;
    int T1 = N * 64;
    int T2 = T1 + 98304;
    if (i < T1) {
        int n = i >> 6, q = i & 63;
        float ns = normOf[n];
        const float* spp = (q < 32) ? &feat[(size_t)n * 128 + q * 4]
                                    : &hx[(size_t)n * 128 + (q - 32) * 4];
        float4 v = *(const float4*)spp;
        short4 p;
        p.x = f2bf(v.x * ns); p.y = f2bf(v.y * ns);
        p.z = f2bf(v.z * ns); p.w = f2bf(v.w * ns);
        *(short4*)&fh[(size_t)n * 256 + q * 4] = p;   // q*4 == 128+(q-32)*4
    } else if (i < T2) {
        int w = i - T1;
        int k = w & 127, n = (w >> 7) & 15, r = w >> 11;
        int gm = r % 6, cb = r / 6;
        const float* Wsrc = (gm < 3) ? Wi : Wh;
        int g = gm % 3;
        Wbf[w] = f2bf(Wsrc[k * 384 + g * 128 + cb * 16 + n]);
    } else {
        int e = i - T2;
        if (e < E) {
            int c = e / chunk;
            int pos = csrOffC[(size_t)c * N + dst[e]] + rank[e];
            srcSorted[pos] = src[e];
        }
    }
}

// ---------------------------------------------------------------------------
// K6: gather-aggregate. One wave per dst node, no LDS, 8 B/lane row reads,
// wave-uniform scalar index loads (R1 structure, 28-VGPR class — proven
// best across R1/R2/R3; the compiler pins MLP regardless of source order).
__global__ __launch_bounds__(256) void gather_kernel(
    const short* __restrict__ fh, const int* __restrict__ csrOff,
    const int* __restrict__ srcSorted, const float* __restrict__ normIf,
    short* __restrict__ agg, int N) {
    int wv = threadIdx.x >> 6, lane = threadIdx.x & 63;
    int d = blockIdx.x * 4 + wv;
    if (d >= N) return;
    const ushort4* fh4 = (const ushort4*)fh;
    int beg = csrOff[d], end = csrOff[d + 1];
    float4 acc = make_float4(0.f, 0.f, 0.f, 0.f);
    #pragma unroll 8
    for (int e = beg; e < end; ++e) {
        int s = srcSorted[e];                     // wave-uniform scalar load
        ushort4 v = fh4[(size_t)s * 64 + lane];   // 8B/lane, 512B/wave
        acc.x += bf2f(v.x); acc.y += bf2f(v.y);
        acc.z += bf2f(v.z); acc.w += bf2f(v.w);
    }
    float nd = normIf[d];
    short4 p;
    p.x = f2bf(acc.x * nd); p.y = f2bf(acc.y * nd);
    p.z = f2bf(acc.z * nd); p.w = f2bf(acc.w * nd);
    *(short4*)&agg[(size_t)d * 256 + lane * 4] = p;
}

// ---------------------------------------------------------------------------
// K7: dense bf16 MFMA GEMM + GRU gates. Weights staged per-cb into LDS via
// global_load_lds (width=16), double-buffered, shared by the 4 waves of the
// block. LDS layout XOR-swizzled (16B slot ^= row&15) on BOTH the global
// source address and the LDS read address -> bank-conflict-free ds_read_b128
// with bit-identical per-lane fragments.
#define GLOAD_LDS16(gp, lp)                                                   \
    __builtin_amdgcn_global_load_lds(                                         \
        (const __attribute__((address_space(1))) void*)(gp),                  \
        (__attribute__((address_space(3))) void*)(lp), 16, 0, 0)

__global__ __launch_bounds__(256, 3) void gemm_gates_kernel(
    const short* __restrict__ agg, const float* __restrict__ hx,
    const short* __restrict__ Wbf,
    const float* __restrict__ bi, const float* __restrict__ bh,
    float* __restrict__ out, int N) {
    __shared__ short wlds[2][12288];            // 2 x 24.6 KB double buffer
    const int tid = threadIdx.x;
    const int wv = tid >> 6, lane = tid & 63;
    const int l15 = lane & 15, quad = lane >> 4;
    const int rowBase = (blockIdx.x * 4 + wv) * 16;
    // N is a multiple of 16, so an active wave always has 16 valid rows.
    // Inactive waves (tail block) must still stage + hit barriers.
    const bool active = rowBase < N;

    // A-fragments preloaded to registers BEFORE any out store (agg aliases
    // out; each wave reads/writes only its own 16 rows -> no hazard).
    int arow = active ? rowBase + l15 : 0;
    const short* aPtr = agg + (size_t)arow * 256;
    bf16x8 aLo[4], aHi[4];
    #pragma unroll
    for (int kst = 0; kst < 4; ++kst) {
        aLo[kst] = *(const bf16x8*)&aPtr[kst * 32 + quad * 8];
        aHi[kst] = *(const bf16x8*)&aPtr[128 + kst * 32 + quad * 8];
    }

    // Prologue: stage cb=0 slab (each wave copies its own 6144 B chunk).
    {
        const char* gs = (const char*)Wbf;
        #pragma unroll
        for (int i = 0; i < 6; ++i) {
            int ldsByte = wv * 6144 + i * 1024 + lane * 16;
            int gByte = ldsByte ^ (((ldsByte >> 8) & 15) << 4);   // slot ^= row&15
            GLOAD_LDS16(gs + gByte, (char*)&wlds[0][0] + wv * 6144 + i * 1024);
        }
    }
    __syncthreads();   // compiler drains vmcnt(0) before s_barrier

    for (int cb = 0; cb < 8; ++cb) {
        const int buf = cb & 1;
        if (cb < 7) {   // async prefetch next slab into the other buffer
            const char* gs = (const char*)(Wbf + (size_t)(cb + 1) * 12288);
            #pragma unroll
            for (int i = 0; i < 6; ++i) {
                int ldsByte = wv * 6144 + i * 1024 + lane * 16;
                int gByte = ldsByte ^ (((ldsByte >> 8) & 15) << 4);
                GLOAD_LDS16(gs + gByte,
                            (char*)&wlds[buf ^ 1][0] + wv * 6144 + i * 1024);
            }
        }
        if (active) {
            f32x4v acc[6];
            #pragma unroll
            for (int g = 0; g < 6; ++g) acc[g] = (f32x4v){0.f, 0.f, 0.f, 0.f};
            const char* slab = (const char*)&wlds[buf][0];
            #pragma unroll
            for (int kst = 0; kst < 4; ++kst) {
                const int co = (((kst * 4 + quad) ^ l15) << 4);   // swizzled col
                #pragma unroll
                for (int g = 0; g < 3; ++g) {
                    bf16x8 bI = *(const bf16x8*)(slab + g * 4096 + l15 * 256 + co);
                    acc[g] = __builtin_amdgcn_mfma_f32_16x16x32_bf16(
                        aLo[kst], bI, acc[g], 0, 0, 0);
                    bf16x8 bH = *(const bf16x8*)(slab + (g + 3) * 4096 + l15 * 256 + co);
                    acc[g + 3] = __builtin_amdgcn_mfma_f32_16x16x32_bf16(
                        aHi[kst], bH, acc[g + 3], 0, 0, 0);
                }
            }
            int ocol = cb * 16 + l15;
            float bir = bi[ocol], biz = bi[128 + ocol], bin = bi[256 + ocol];
            float bhr = bh[ocol], bhz = bh[128 + ocol], bhn = bh[256 + ocol];
            #pragma unroll
            for (int reg = 0; reg < 4; ++reg) {
                int row = rowBase + quad * 4 + reg;
                float ir = acc[0][reg] + bir, iz = acc[1][reg] + biz, in_ = acc[2][reg] + bin;
                float hr = acc[3][reg] + bhr, hz = acc[4][reg] + bhz, hn = acc[5][reg] + bhn;
                float rg = 1.0f / (1.0f + __expf(-(ir + hr)));
                float zg = 1.0f / (1.0f + __expf(-(iz + hz)));
                float ng = tanhf(in_ + rg * hn);
                float hv = hx[(size_t)row * DIM + ocol];
                out[(size_t)row * DIM + ocol] = (1.0f - zg) * ng + zg * hv;
            }
        }
        __syncthreads();   // drains this iter's prefetch; protects buf reuse
    }
}

// ---------------------------------------------------------------------------
extern "C" void kernel_launch(void* const* d_in, const int* in_sizes, int n_in,
                              void* d_out, int out_size, void* d_ws, size_t ws_size,
                              hipStream_t stream) {
    const float* feat = (const float*)d_in[0];
    const float* hx   = (const float*)d_in[1];
    const float* Wi   = (const float*)d_in[2];
    const float* bi   = (const float*)d_in[3];
    const float* Wh   = (const float*)d_in[4];
    const float* bh   = (const float*)d_in[5];
    const int* src    = (const int*)d_in[6];
    const int* dst    = (const int*)d_in[7];
    float* out        = (float*)d_out;

    int N = in_sizes[0] / DIM;   // 50000
    int E = in_sizes[6];         // 800000
    int rgsz  = (N + 7) / 8;     // 6250 (<= RGMAX)
    int nrg   = (N + rgsz - 1) / rgsz;   // 8
    int chunk = (E + NCH - 1) / NCH;     // 25000
    int NB    = (N + 255) / 256;         // 196 (<= 256 for the LDS scan)

    int* wsi = (int*)d_ws;
    int* partI     = wsi;                       // NCH*N
    int* partO     = wsi + (size_t)NCH * N;     // NCH*N (k_off rewrites as csrOffC)
    int* csrOff    = wsi + (size_t)2 * NCH * N; // N+1
    int* srcSorted = csrOff + N + 1;            // E
    int* rank      = srcSorted + E;             // E
    int* bsum      = rank + E;                  // 256
    float* normIf  = (float*)(bsum + 256);      // N
    float* normOf  = normIf + N;                // N
    size_t iend = (size_t)(2 * NCH * N + N + 1 + 2 * E + 256 + 2 * N);
    size_t wofs = (iend * 4 + 15) & ~(size_t)15;
    short* Wbf = (short*)((char*)d_ws + wofs);         // 98304 bf16
    size_t fofs = (wofs + 98304 * 2 + 15) & ~(size_t)15;
    short* fh = (short*)((char*)d_ws + fofs);          // N*256 bf16 (~25.6MB)
    // total ws: ~45.6 MB (proven-safe budget: 51.6 MB)
    short* agg = (short*)d_out;  // bf16 agg aliased over d_out

    k_hist<<<NCH * nrg, 256, 0, stream>>>(src, dst, partO, partI, rank,
                                          N, E, chunk, rgsz);
    k_bsum<<<NB, 256, 0, stream>>>(partI, bsum, N);
    k_off<<<NB, 256, 0, stream>>>(partI, partO, bsum, csrOff,
                                  normIf, normOf, N, NB);
    k_xcw<<<(N * 64 + 98304 + E + 255) / 256, 256, 0, stream>>>(
        feat, hx, Wi, Wh, normOf, Wbf, fh,
        src, dst, rank, partO /*csrOffC*/, srcSorted, N, E, chunk);

    gather_kernel<<<(N + 3) / 4, 256, 0, stream>>>(
        fh, csrOff, srcSorted, normIf, agg, N);
    gemm_gates_kernel<<<(N + 63) / 64, 256, 0, stream>>>(
        agg, hx, Wbf, bi, bh, out, N);
}

// Round 7
// 266.811 us; speedup vs baseline: 1.2678x; 1.0346x over previous
//
#include <hip/hip_runtime.h>
#include <math.h>

#define DIM 128
#define NCH 32          // edge chunks (partial-histogram count)
#define RGMAX 6272      // max nodes per LDS range (2*RGMAX*4 = 50 KB LDS)

typedef float f32x4v __attribute__((ext_vector_type(4)));
typedef short bf16x8 __attribute__((ext_vector_type(8)));

static __device__ __forceinline__ short f2bf(float f) {
    unsigned u = __float_as_uint(f);
    unsigned r = (u + 0x7fffu + ((u >> 16) & 1u)) >> 16;   // RNE
    return (short)r;
}
static __device__ __forceinline__ float bf2f(unsigned short s) {
    return __uint_as_float(((unsigned)s) << 16);
}

// ---------------------------------------------------------------------------
// K1: LDS-histogram degree count, NO global atomics (R4/R5: global atomics
// cost a fixed ~53 ns/KB fabric write-through regardless of scope/replication).
// (chunk x range) grid; block (c,r) streams edge chunk c, counts keys in node
// range r into LDS via ds_add_rtn; returned old value = intra-(chunk,dst)
// rank -> atomic-free counting sort downstream.
// NEW (this round): 512 threads/block — grid is 256 blocks (1/CU), so wider
// blocks double resident waves/CU (4->8) and halve the serial scan depth.
// Rank stays a bijection per (chunk,dst) (arrival order is irrelevant).
__global__ __launch_bounds__(512) void k_hist(const int* __restrict__ src,
                                              const int* __restrict__ dst,
                                              int* __restrict__ partO,
                                              int* __restrict__ partI,
                                              int* __restrict__ rank,
                                              int N, int E, int chunk, int rgsz) {
    __shared__ int hO[RGMAX], hI[RGMAX];
    int t = threadIdx.x;
    int c = blockIdx.x % NCH, r = blockIdx.x / NCH;
    int lo = r * rgsz;
    int hi = min(lo + rgsz, N);
    for (int i = t; i < rgsz; i += 512) { hO[i] = 0; hI[i] = 0; }
    __syncthreads();
    int e0 = c * chunk, e1 = min(e0 + chunk, E);
    for (int e = e0 + t; e < e1; e += 512) {
        int s = src[e], d = dst[e];
        if (s >= lo && s < hi) atomicAdd(&hO[s - lo], 1);          // LDS atomic
        if (d >= lo && d < hi) rank[e] = atomicAdd(&hI[d - lo], 1);
    }
    __syncthreads();
    for (int i = t; i < hi - lo; i += 512) {
        partO[(size_t)c * N + lo + i] = hO[i];
        partI[(size_t)c * N + lo + i] = hI[i];
    }
}

// K2: per-256-node block sums of degI (over the NCH chunk partials).
__global__ __launch_bounds__(256) void k_bsum(const int* __restrict__ partI,
                                              int* __restrict__ bsum, int N) {
    __shared__ int red[4];
    int b = blockIdx.x, t = threadIdx.x;
    int n = b * 256 + t;
    int s = 0;
    if (n < N) {
        #pragma unroll
        for (int c = 0; c < NCH; ++c) s += partI[(size_t)c * N + n];
    }
    for (int off = 32; off; off >>= 1) s += __shfl_down(s, off);
    if ((t & 63) == 0) red[t >> 6] = s;
    __syncthreads();
    if (t == 0) bsum[b] = red[0] + red[1] + red[2] + red[3];
}

// K3: exclusive scan -> csrOff + per-chunk bases csrOffC + norm factors.
// One node per thread, NB <= 256 blocks, LDS Hillis-Steele scans.
// csrOffC ALIASES partO (same pointer): each thread reads its partO entries
// before overwriting the same addresses -> safe (thread-private indices).
__global__ __launch_bounds__(256) void k_off(const int* __restrict__ partI,
                                             int* partO_csrC,   // in: partO, out: csrOffC
                                             const int* __restrict__ bsum,
                                             int* __restrict__ csrOff,
                                             float* __restrict__ normIf,
                                             float* __restrict__ normOf,
                                             int N, int NB) {
    __shared__ int sp[256];
    __shared__ int sbase;
    int b = blockIdx.x, t = threadIdx.x;
    int own = (t < NB) ? bsum[t] : 0;
    sp[t] = own;
    __syncthreads();
    for (int off = 1; off < 256; off <<= 1) {
        int u = (t >= off) ? sp[t - off] : 0;
        __syncthreads();
        sp[t] += u;
        __syncthreads();
    }
    if (t == b) sbase = sp[t] - own;
    if (b == 0 && t == NB - 1) csrOff[N] = sp[t];
    __syncthreads();
    int n = b * 256 + t;
    int cv[NCH];
    int tI = 0, tO = 0;
    if (n < N) {
        #pragma unroll
        for (int c = 0; c < NCH; ++c) {
            cv[c] = partI[(size_t)c * N + n];
            tI += cv[c];
            tO += partO_csrC[(size_t)c * N + n];
        }
    }
    sp[t] = tI;
    __syncthreads();
    for (int off = 1; off < 256; off <<= 1) {
        int u = (t >= off) ? sp[t - off] : 0;
        __syncthreads();
        sp[t] += u;
        __syncthreads();
    }
    int o = sbase + sp[t] - tI;
    if (n < N) {
        csrOff[n] = o;
        normIf[n] = rsqrtf(fmaxf((float)tI, 1.0f));
        normOf[n] = rsqrtf(fmaxf((float)tO, 1.0f));
        int base = o;
        #pragma unroll
        for (int c = 0; c < NCH; ++c) {
            partO_csrC[(size_t)c * N + n] = base;   // csrOffC[c][n]
            base += cv[c];
        }
    }
}

// K4: merged pre-scaled bf16 feat/hx + bf16 weight convert + atomic-free
// counting-sort fill (pos = csrOffC[e/chunk][dst] + rank).
__global__ __launch_bounds__(256) void k_xcw(const float* __restrict__ feat,
                                             const float* __restrict__ hx,
                                             const float* __restrict__ Wi,
                                             const float* __restrict__ Wh,
                                             const float* __restrict__ normOf,
                                             short* __restrict__ Wbf,
                                             short* __restrict__ fh,
                                             const int* __restrict__ src,
                                             const int* __restrict__ dst,
                                             const int* __restrict__ rank,
                                             const int* __restrict__ csrOffC,
                                             int* __restrict__ srcSorted,
                                             int N, int E, int chunk) {
    int i = blockIdx.x * 256 + threadIdx.x;
    int T1 = N * 64;
    int T2 = T1 + 98304;
    if (i < T1) {
        int n = i >> 6, q = i & 63;
        float ns = normOf[n];
        const float* spp = (q < 32) ? &feat[(size_t)n * 128 + q * 4]
                                    : &hx[(size_t)n * 128 + (q - 32) * 4];
        float4 v = *(const float4*)spp;
        short4 p;
        p.x = f2bf(v.x * ns); p.y = f2bf(v.y * ns);
        p.z = f2bf(v.z * ns); p.w = f2bf(v.w * ns);
        *(short4*)&fh[(size_t)n * 256 + q * 4] = p;   // q*4 == 128+(q-32)*4
    } else if (i < T2) {
        int w = i - T1;
        int k = w & 127, n = (w >> 7) & 15, r = w >> 11;
        int gm = r % 6, cb = r / 6;
        const float* Wsrc = (gm < 3) ? Wi : Wh;
        int g = gm % 3;
        Wbf[w] = f2bf(Wsrc[k * 384 + g * 128 + cb * 16 + n]);
    } else {
        int e = i - T2;
        if (e < E) {
            int c = e / chunk;
            int pos = csrOffC[(size_t)c * N + dst[e]] + rank[e];
            srcSorted[pos] = src[e];
        }
    }
}

// ---------------------------------------------------------------------------
// K6: gather-aggregate. One wave per dst node, no LDS, 8 B/lane row reads.
// NEW (this round): the per-edge index comes from a REGISTER (__shfl out of a
// 64-wide batch loaded with one coalesced vector load), not from a per-edge
// wave-uniform s_load. R1/R3 showed the compiler pins the chain
// s_load(~200cy) -> addr -> row load(~450cy); replacing the s_load with a
// ~25cy shfl shortens the serial chain and makes successive row loads
// memory-independent so they can pipeline. Edge accumulation order is
// unchanged -> numerics bit-identical.
__global__ __launch_bounds__(256) void gather_kernel(
    const short* __restrict__ fh, const int* __restrict__ csrOff,
    const int* __restrict__ srcSorted, const float* __restrict__ normIf,
    short* __restrict__ agg, int N) {
    int wv = threadIdx.x >> 6, lane = threadIdx.x & 63;
    int d = blockIdx.x * 4 + wv;
    if (d >= N) return;
    const ushort4* fh4 = (const ushort4*)fh;
    int beg = csrOff[d], end = csrOff[d + 1];
    float4 acc = make_float4(0.f, 0.f, 0.f, 0.f);
    for (int b0 = beg; b0 < end; b0 += 64) {
        int ie = b0 + lane;
        int sidx = srcSorted[ie < end ? ie : end - 1];   // one 256B batch load
        int cnt = min(64, end - b0);
        #pragma unroll 4
        for (int j = 0; j < cnt; ++j) {
            int s = __shfl(sidx, j);                     // register, ~25 cy
            ushort4 v = fh4[(size_t)s * 64 + lane];      // 8B/lane, 512B/wave
            acc.x += bf2f(v.x); acc.y += bf2f(v.y);
            acc.z += bf2f(v.z); acc.w += bf2f(v.w);
        }
    }
    float nd = normIf[d];
    short4 p;
    p.x = f2bf(acc.x * nd); p.y = f2bf(acc.y * nd);
    p.z = f2bf(acc.z * nd); p.w = f2bf(acc.w * nd);
    *(short4*)&agg[(size_t)d * 256 + lane * 4] = p;
}

// ---------------------------------------------------------------------------
// K7: dense bf16 MFMA GEMM + GRU gates. Weights staged per-cb into LDS via
// global_load_lds (width=16), double-buffered, shared by the 4 waves of the
// block. LDS layout XOR-swizzled (16B slot ^= row&15) on BOTH the global
// source address and the LDS read address -> bank-conflict-free ds_read_b128
// with bit-identical per-lane fragments.
#define GLOAD_LDS16(gp, lp)                                                   \
    __builtin_amdgcn_global_load_lds(                                         \
        (const __attribute__((address_space(1))) void*)(gp),                  \
        (__attribute__((address_space(3))) void*)(lp), 16, 0, 0)

__global__ __launch_bounds__(256, 3) void gemm_gates_kernel(
    const short* __restrict__ agg, const float* __restrict__ hx,
    const short* __restrict__ Wbf,
    const float* __restrict__ bi, const float* __restrict__ bh,
    float* __restrict__ out, int N) {
    __shared__ short wlds[2][12288];            // 2 x 24.6 KB double buffer
    const int tid = threadIdx.x;
    const int wv = tid >> 6, lane = tid & 63;
    const int l15 = lane & 15, quad = lane >> 4;
    const int rowBase = (blockIdx.x * 4 + wv) * 16;
    // N is a multiple of 16, so an active wave always has 16 valid rows.
    // Inactive waves (tail block) must still stage + hit barriers.
    const bool active = rowBase < N;

    // A-fragments preloaded to registers BEFORE any out store (agg aliases
    // out; each wave reads/writes only its own 16 rows -> no hazard).
    int arow = active ? rowBase + l15 : 0;
    const short* aPtr = agg + (size_t)arow * 256;
    bf16x8 aLo[4], aHi[4];
    #pragma unroll
    for (int kst = 0; kst < 4; ++kst) {
        aLo[kst] = *(const bf16x8*)&aPtr[kst * 32 + quad * 8];
        aHi[kst] = *(const bf16x8*)&aPtr[128 + kst * 32 + quad * 8];
    }

    // Prologue: stage cb=0 slab (each wave copies its own 6144 B chunk).
    {
        const char* gs = (const char*)Wbf;
        #pragma unroll
        for (int i = 0; i < 6; ++i) {
            int ldsByte = wv * 6144 + i * 1024 + lane * 16;
            int gByte = ldsByte ^ (((ldsByte >> 8) & 15) << 4);   // slot ^= row&15
            GLOAD_LDS16(gs + gByte, (char*)&wlds[0][0] + wv * 6144 + i * 1024);
        }
    }
    __syncthreads();   // compiler drains vmcnt(0) before s_barrier

    for (int cb = 0; cb < 8; ++cb) {
        const int buf = cb & 1;
        if (cb < 7) {   // async prefetch next slab into the other buffer
            const char* gs = (const char*)(Wbf + (size_t)(cb + 1) * 12288);
            #pragma unroll
            for (int i = 0; i < 6; ++i) {
                int ldsByte = wv * 6144 + i * 1024 + lane * 16;
                int gByte = ldsByte ^ (((ldsByte >> 8) & 15) << 4);
                GLOAD_LDS16(gs + gByte,
                            (char*)&wlds[buf ^ 1][0] + wv * 6144 + i * 1024);
            }
        }
        if (active) {
            f32x4v acc[6];
            #pragma unroll
            for (int g = 0; g < 6; ++g) acc[g] = (f32x4v){0.f, 0.f, 0.f, 0.f};
            const char* slab = (const char*)&wlds[buf][0];
            #pragma unroll
            for (int kst = 0; kst < 4; ++kst) {
                const int co = (((kst * 4 + quad) ^ l15) << 4);   // swizzled col
                #pragma unroll
                for (int g = 0; g < 3; ++g) {
                    bf16x8 bI = *(const bf16x8*)(slab + g * 4096 + l15 * 256 + co);
                    acc[g] = __builtin_amdgcn_mfma_f32_16x16x32_bf16(
                        aLo[kst], bI, acc[g], 0, 0, 0);
                    bf16x8 bH = *(const bf16x8*)(slab + (g + 3) * 4096 + l15 * 256 + co);
                    acc[g + 3] = __builtin_amdgcn_mfma_f32_16x16x32_bf16(
                        aHi[kst], bH, acc[g + 3], 0, 0, 0);
                }
            }
            int ocol = cb * 16 + l15;
            float bir = bi[ocol], biz = bi[128 + ocol], bin = bi[256 + ocol];
            float bhr = bh[ocol], bhz = bh[128 + ocol], bhn = bh[256 + ocol];
            #pragma unroll
            for (int reg = 0; reg < 4; ++reg) {
                int row = rowBase + quad * 4 + reg;
                float ir = acc[0][reg] + bir, iz = acc[1][reg] + biz, in_ = acc[2][reg] + bin;
                float hr = acc[3][reg] + bhr, hz = acc[4][reg] + bhz, hn = acc[5][reg] + bhn;
                float rg = 1.0f / (1.0f + __expf(-(ir + hr)));
                float zg = 1.0f / (1.0f + __expf(-(iz + hz)));
                float ng = tanhf(in_ + rg * hn);
                float hv = hx[(size_t)row * DIM + ocol];
                out[(size_t)row * DIM + ocol] = (1.0f - zg) * ng + zg * hv;
            }
        }
        __syncthreads();   // drains this iter's prefetch; protects buf reuse
    }
}

// ---------------------------------------------------------------------------
extern "C" void kernel_launch(void* const* d_in, const int* in_sizes, int n_in,
                              void* d_out, int out_size, void* d_ws, size_t ws_size,
                              hipStream_t stream) {
    const float* feat = (const float*)d_in[0];
    const float* hx   = (const float*)d_in[1];
    const float* Wi   = (const float*)d_in[2];
    const float* bi   = (const float*)d_in[3];
    const float* Wh   = (const float*)d_in[4];
    const float* bh   = (const float*)d_in[5];
    const int* src    = (const int*)d_in[6];
    const int* dst    = (const int*)d_in[7];
    float* out        = (float*)d_out;

    int N = in_sizes[0] / DIM;   // 50000
    int E = in_sizes[6];         // 800000
    int rgsz  = (N + 7) / 8;     // 6250 (<= RGMAX)
    int nrg   = (N + rgsz - 1) / rgsz;   // 8
    int chunk = (E + NCH - 1) / NCH;     // 25000
    int NB    = (N + 255) / 256;         // 196 (<= 256 for the LDS scan)

    int* wsi = (int*)d_ws;
    int* partI     = wsi;                       // NCH*N
    int* partO     = wsi + (size_t)NCH * N;     // NCH*N (k_off rewrites as csrOffC)
    int* csrOff    = wsi + (size_t)2 * NCH * N; // N+1
    int* srcSorted = csrOff + N + 1;            // E
    int* rank      = srcSorted + E;             // E
    int* bsum      = rank + E;                  // 256
    float* normIf  = (float*)(bsum + 256);      // N
    float* normOf  = normIf + N;                // N
    size_t iend = (size_t)(2 * NCH * N + N + 1 + 2 * E + 256 + 2 * N);
    size_t wofs = (iend * 4 + 15) & ~(size_t)15;
    short* Wbf = (short*)((char*)d_ws + wofs);         // 98304 bf16
    size_t fofs = (wofs + 98304 * 2 + 15) & ~(size_t)15;
    short* fh = (short*)((char*)d_ws + fofs);          // N*256 bf16 (~25.6MB)
    // total ws: ~45.6 MB (proven-safe budget: 51.6 MB)
    short* agg = (short*)d_out;  // bf16 agg aliased over d_out

    k_hist<<<NCH * nrg, 512, 0, stream>>>(src, dst, partO, partI, rank,
                                          N, E, chunk, rgsz);
    k_bsum<<<NB, 256, 0, stream>>>(partI, bsum, N);
    k_off<<<NB, 256, 0, stream>>>(partI, partO, bsum, csrOff,
                                  normIf, normOf, N, NB);
    k_xcw<<<(N * 64 + 98304 + E + 255) / 256, 256, 0, stream>>>(
        feat, hx, Wi, Wh, normOf, Wbf, fh,
        src, dst, rank, partO /*csrOffC*/, srcSorted, N, E, chunk);

    gather_kernel<<<(N + 3) / 4, 256, 0, stream>>>(
        fh, csrOff, srcSorted, normIf, agg, N);
    gemm_gates_kernel<<<(N + 63) / 64, 256, 0, stream>>>(
        agg, hx, Wbf, bi, bh, out, N);
}

// Round 8
// 251.018 us; speedup vs baseline: 1.3476x; 1.0629x over previous
//
#include <hip/hip_runtime.h>
#include <math.h>

#define DIM 128
#define NCH 32          // edge chunks; per-chunk per-node count < 65536 -> u16
#define NMAXW 25024     // LDS histogram words (covers N <= 50048)

typedef float f32x4v __attribute__((ext_vector_type(4)));
typedef short bf16x8 __attribute__((ext_vector_type(8)));

static __device__ __forceinline__ short f2bf(float f) {
    unsigned u = __float_as_uint(f);
    unsigned r = (u + 0x7fffu + ((u >> 16) & 1u)) >> 16;   // RNE
    return (short)r;
}
static __device__ __forceinline__ float bf2f(unsigned short s) {
    return __uint_as_float(((unsigned)s) << 16);
}

// ---------------------------------------------------------------------------
// K1: ONE-PASS full-N LDS histogram per edge chunk (u16 packed counters).
// R6/R7's (chunk x range) grid read the edge arrays 8x and wrote rank at 1/8
// line density (8-XCD partial-line amplification). Per-chunk counts < 65536,
// so a full-N u16 histogram is 100 KB -> fits LDS. Packed u16 atomics on u32
// words: halves can't carry into each other (each half < 2^16). Blocks
// [0,NCH) do the dst histogram + rank (dense coalesced u16 write); blocks
// [NCH,2NCH) do the src histogram. Edge reads: 6.4 MB total, once.
__global__ __launch_bounds__(1024) void k_hist(const int* __restrict__ src,
                                               const int* __restrict__ dst,
                                               unsigned short* __restrict__ partO,
                                               unsigned short* __restrict__ partI,
                                               unsigned short* __restrict__ rank,
                                               int N, int Npad, int E, int chunk) {
    __shared__ unsigned int h[NMAXW];
    int t = threadIdx.x;
    int isI = blockIdx.x < NCH;
    int c = isI ? blockIdx.x : blockIdx.x - NCH;
    int NW = (N + 1) >> 1;
    for (int i = t; i < NW; i += 1024) h[i] = 0;
    __syncthreads();
    int e0 = c * chunk, e1 = min(e0 + chunk, E);
    if (isI) {
        for (int e = e0 + t; e < e1; e += 1024) {
            int d = dst[e];
            unsigned sh = (d & 1) * 16;
            unsigned old = atomicAdd(&h[d >> 1], 1u << sh);   // LDS atomic
            rank[e] = (unsigned short)((old >> sh) & 0xffffu);
        }
    } else {
        for (int e = e0 + t; e < e1; e += 1024) {
            int s = src[e];
            atomicAdd(&h[s >> 1], 1u << ((s & 1) * 16));
        }
    }
    __syncthreads();
    unsigned int* p = (unsigned int*)((isI ? partI : partO) + (size_t)c * Npad);
    for (int i = t; i < NW; i += 1024) p[i] = h[i];   // u16 pair per word
}

// K2: per-256-node block sums of degI (over the NCH chunk partials).
__global__ __launch_bounds__(256) void k_bsum(const unsigned short* __restrict__ partI,
                                              int* __restrict__ bsum, int N, int Npad) {
    __shared__ int red[4];
    int b = blockIdx.x, t = threadIdx.x;
    int n = b * 256 + t;
    int s = 0;
    if (n < N) {
        #pragma unroll
        for (int c = 0; c < NCH; ++c) s += partI[(size_t)c * Npad + n];
    }
    for (int off = 32; off; off >>= 1) s += __shfl_down(s, off);
    if ((t & 63) == 0) red[t >> 6] = s;
    __syncthreads();
    if (t == 0) bsum[b] = red[0] + red[1] + red[2] + red[3];
}

// K3: exclusive scan -> csrOff + per-chunk bases csrOffC + norm factors.
// One node per thread, NB <= 256 blocks, LDS Hillis-Steele scans.
__global__ __launch_bounds__(256) void k_off(const unsigned short* __restrict__ partI,
                                             const unsigned short* __restrict__ partO,
                                             const int* __restrict__ bsum,
                                             int* __restrict__ csrOffC,
                                             int* __restrict__ csrOff,
                                             float* __restrict__ normIf,
                                             float* __restrict__ normOf,
                                             int N, int Npad, int NB) {
    __shared__ int sp[256];
    __shared__ int sbase;
    int b = blockIdx.x, t = threadIdx.x;
    int own = (t < NB) ? bsum[t] : 0;
    sp[t] = own;
    __syncthreads();
    for (int off = 1; off < 256; off <<= 1) {
        int u = (t >= off) ? sp[t - off] : 0;
        __syncthreads();
        sp[t] += u;
        __syncthreads();
    }
    if (t == b) sbase = sp[t] - own;
    if (b == 0 && t == NB - 1) csrOff[N] = sp[t];
    __syncthreads();
    int n = b * 256 + t;
    int cv[NCH];
    int tI = 0, tO = 0;
    if (n < N) {
        #pragma unroll
        for (int c = 0; c < NCH; ++c) {
            cv[c] = partI[(size_t)c * Npad + n];
            tI += cv[c];
            tO += partO[(size_t)c * Npad + n];
        }
    }
    sp[t] = tI;
    __syncthreads();
    for (int off = 1; off < 256; off <<= 1) {
        int u = (t >= off) ? sp[t - off] : 0;
        __syncthreads();
        sp[t] += u;
        __syncthreads();
    }
    int o = sbase + sp[t] - tI;
    if (n < N) {
        csrOff[n] = o;
        normIf[n] = rsqrtf(fmaxf((float)tI, 1.0f));
        normOf[n] = rsqrtf(fmaxf((float)tO, 1.0f));
        int base = o;
        #pragma unroll
        for (int c = 0; c < NCH; ++c) {
            csrOffC[(size_t)c * N + n] = base;
            base += cv[c];
        }
    }
}

// K4: merged pre-scaled bf16 feat/hx + bf16 weight convert + atomic-free
// counting-sort fill (pos = csrOffC[e/chunk][dst] + rank).
__global__ __launch_bounds__(256) void k_xcw(const float* __restrict__ feat,
                                             const float* __restrict__ hx,
                                             const float* __restrict__ Wi,
                                             const float* __restrict__ Wh,
                                             const float* __restrict__ normOf,
                                             short* __restrict__ Wbf,
                                             short* __restrict__ fh,
                                             const int* __restrict__ src,
                                             const int* __restrict__ dst,
                                             const unsigned short* __restrict__ rank,
                                             const int* __restrict__ csrOffC,
                                             int* __restrict__ srcSorted,
                                             int N, int E, int chunk) {
    int i = blockIdx.x * 256 + threadIdx.x;
    int T1 = N * 64;
    int T2 = T1 + 98304;
    if (i < T1) {
        int n = i >> 6, q = i & 63;
        float ns = normOf[n];
        const float* spp = (q < 32) ? &feat[(size_t)n * 128 + q * 4]
                                    : &hx[(size_t)n * 128 + (q - 32) * 4];
        float4 v = *(const float4*)spp;
        short4 p;
        p.x = f2bf(v.x * ns); p.y = f2bf(v.y * ns);
        p.z = f2bf(v.z * ns); p.w = f2bf(v.w * ns);
        *(short4*)&fh[(size_t)n * 256 + q * 4] = p;   // q*4 == 128+(q-32)*4
    } else if (i < T2) {
        int w = i - T1;
        int k = w & 127, n = (w >> 7) & 15, r = w >> 11;
        int gm = r % 6, cb = r / 6;
        const float* Wsrc = (gm < 3) ? Wi : Wh;
        int g = gm % 3;
        Wbf[w] = f2bf(Wsrc[k * 384 + g * 128 + cb * 16 + n]);
    } else {
        int e = i - T2;
        if (e < E) {
            int c = e / chunk;
            int pos = csrOffC[(size_t)c * N + dst[e]] + (int)rank[e];
            srcSorted[pos] = src[e];
        }
    }
}

// ---------------------------------------------------------------------------
// K6: gather-aggregate. One wave per dst node, no LDS, 8 B/lane row reads,
// wave-uniform scalar index loads. R1 structure — proven floor (~65 us)
// across R1/R2/R3/R7; every MLP-raising rewrite (half-wave split, explicit
// batch, shfl-broadcast) was neutral or regressed. Do not touch.
__global__ __launch_bounds__(256) void gather_kernel(
    const short* __restrict__ fh, const int* __restrict__ csrOff,
    const int* __restrict__ srcSorted, const float* __restrict__ normIf,
    short* __restrict__ agg, int N) {
    int wv = threadIdx.x >> 6, lane = threadIdx.x & 63;
    int d = blockIdx.x * 4 + wv;
    if (d >= N) return;
    const ushort4* fh4 = (const ushort4*)fh;
    int beg = csrOff[d], end = csrOff[d + 1];
    float4 acc = make_float4(0.f, 0.f, 0.f, 0.f);
    #pragma unroll 8
    for (int e = beg; e < end; ++e) {
        int s = srcSorted[e];                     // wave-uniform scalar load
        ushort4 v = fh4[(size_t)s * 64 + lane];   // 8B/lane, 512B/wave
        acc.x += bf2f(v.x); acc.y += bf2f(v.y);
        acc.z += bf2f(v.z); acc.w += bf2f(v.w);
    }
    float nd = normIf[d];
    short4 p;
    p.x = f2bf(acc.x * nd); p.y = f2bf(acc.y * nd);
    p.z = f2bf(acc.z * nd); p.w = f2bf(acc.w * nd);
    *(short4*)&agg[(size_t)d * 256 + lane * 4] = p;
}

// ---------------------------------------------------------------------------
// K7: dense bf16 MFMA GEMM + GRU gates. Weights staged per-cb into LDS via
// global_load_lds (width=16), double-buffered, shared by the 4 waves of the
// block. LDS layout XOR-swizzled (16B slot ^= row&15) on BOTH the global
// source address and the LDS read address -> bank-conflict-free ds_read_b128
// with bit-identical per-lane fragments.
#define GLOAD_LDS16(gp, lp)                                                   \
    __builtin_amdgcn_global_load_lds(                                         \
        (const __attribute__((address_space(1))) void*)(gp),                  \
        (__attribute__((address_space(3))) void*)(lp), 16, 0, 0)

__global__ __launch_bounds__(256, 3) void gemm_gates_kernel(
    const short* __restrict__ agg, const float* __restrict__ hx,
    const short* __restrict__ Wbf,
    const float* __restrict__ bi, const float* __restrict__ bh,
    float* __restrict__ out, int N) {
    __shared__ short wlds[2][12288];            // 2 x 24.6 KB double buffer
    const int tid = threadIdx.x;
    const int wv = tid >> 6, lane = tid & 63;
    const int l15 = lane & 15, quad = lane >> 4;
    const int rowBase = (blockIdx.x * 4 + wv) * 16;
    // N is a multiple of 16, so an active wave always has 16 valid rows.
    // Inactive waves (tail block) must still stage + hit barriers.
    const bool active = rowBase < N;

    // A-fragments preloaded to registers BEFORE any out store (agg aliases
    // out; each wave reads/writes only its own 16 rows -> no hazard).
    int arow = active ? rowBase + l15 : 0;
    const short* aPtr = agg + (size_t)arow * 256;
    bf16x8 aLo[4], aHi[4];
    #pragma unroll
    for (int kst = 0; kst < 4; ++kst) {
        aLo[kst] = *(const bf16x8*)&aPtr[kst * 32 + quad * 8];
        aHi[kst] = *(const bf16x8*)&aPtr[128 + kst * 32 + quad * 8];
    }

    // Prologue: stage cb=0 slab (each wave copies its own 6144 B chunk).
    {
        const char* gs = (const char*)Wbf;
        #pragma unroll
        for (int i = 0; i < 6; ++i) {
            int ldsByte = wv * 6144 + i * 1024 + lane * 16;
            int gByte = ldsByte ^ (((ldsByte >> 8) & 15) << 4);   // slot ^= row&15
            GLOAD_LDS16(gs + gByte, (char*)&wlds[0][0] + wv * 6144 + i * 1024);
        }
    }
    __syncthreads();   // compiler drains vmcnt(0) before s_barrier

    for (int cb = 0; cb < 8; ++cb) {
        const int buf = cb & 1;
        if (cb < 7) {   // async prefetch next slab into the other buffer
            const char* gs = (const char*)(Wbf + (size_t)(cb + 1) * 12288);
            #pragma unroll
            for (int i = 0; i < 6; ++i) {
                int ldsByte = wv * 6144 + i * 1024 + lane * 16;
                int gByte = ldsByte ^ (((ldsByte >> 8) & 15) << 4);
                GLOAD_LDS16(gs + gByte,
                            (char*)&wlds[buf ^ 1][0] + wv * 6144 + i * 1024);
            }
        }
        if (active) {
            f32x4v acc[6];
            #pragma unroll
            for (int g = 0; g < 6; ++g) acc[g] = (f32x4v){0.f, 0.f, 0.f, 0.f};
            const char* slab = (const char*)&wlds[buf][0];
            #pragma unroll
            for (int kst = 0; kst < 4; ++kst) {
                const int co = (((kst * 4 + quad) ^ l15) << 4);   // swizzled col
                #pragma unroll
                for (int g = 0; g < 3; ++g) {
                    bf16x8 bI = *(const bf16x8*)(slab + g * 4096 + l15 * 256 + co);
                    acc[g] = __builtin_amdgcn_mfma_f32_16x16x32_bf16(
                        aLo[kst], bI, acc[g], 0, 0, 0);
                    bf16x8 bH = *(const bf16x8*)(slab + (g + 3) * 4096 + l15 * 256 + co);
                    acc[g + 3] = __builtin_amdgcn_mfma_f32_16x16x32_bf16(
                        aHi[kst], bH, acc[g + 3], 0, 0, 0);
                }
            }
            int ocol = cb * 16 + l15;
            float bir = bi[ocol], biz = bi[128 + ocol], bin = bi[256 + ocol];
            float bhr = bh[ocol], bhz = bh[128 + ocol], bhn = bh[256 + ocol];
            #pragma unroll
            for (int reg = 0; reg < 4; ++reg) {
                int row = rowBase + quad * 4 + reg;
                float ir = acc[0][reg] + bir, iz = acc[1][reg] + biz, in_ = acc[2][reg] + bin;
                float hr = acc[3][reg] + bhr, hz = acc[4][reg] + bhz, hn = acc[5][reg] + bhn;
                float rg = 1.0f / (1.0f + __expf(-(ir + hr)));
                float zg = 1.0f / (1.0f + __expf(-(iz + hz)));
                float ng = tanhf(in_ + rg * hn);
                float hv = hx[(size_t)row * DIM + ocol];
                out[(size_t)row * DIM + ocol] = (1.0f - zg) * ng + zg * hv;
            }
        }
        __syncthreads();   // drains this iter's prefetch; protects buf reuse
    }
}

// ---------------------------------------------------------------------------
extern "C" void kernel_launch(void* const* d_in, const int* in_sizes, int n_in,
                              void* d_out, int out_size, void* d_ws, size_t ws_size,
                              hipStream_t stream) {
    const float* feat = (const float*)d_in[0];
    const float* hx   = (const float*)d_in[1];
    const float* Wi   = (const float*)d_in[2];
    const float* bi   = (const float*)d_in[3];
    const float* Wh   = (const float*)d_in[4];
    const float* bh   = (const float*)d_in[5];
    const int* src    = (const int*)d_in[6];
    const int* dst    = (const int*)d_in[7];
    float* out        = (float*)d_out;

    int N = in_sizes[0] / DIM;   // 50000
    int E = in_sizes[6];         // 800000
    int Npad = (N + 1) & ~1;     // even stride for u16-pair word copies
    int chunk = (E + NCH - 1) / NCH;     // 25000 (< 65536 -> u16 counters)
    int NB    = (N + 255) / 256;         // 196 (<= 256 for the LDS scan)

    unsigned short* partI = (unsigned short*)d_ws;            // NCH*Npad u16
    unsigned short* partO = partI + (size_t)NCH * Npad;       // NCH*Npad u16
    int* csrOffC   = (int*)(partO + (size_t)NCH * Npad);      // NCH*N
    int* csrOff    = csrOffC + (size_t)NCH * N;               // N+1
    int* srcSorted = csrOff + N + 1;                          // E
    unsigned short* rank = (unsigned short*)(srcSorted + E);  // E u16
    int* bsum      = (int*)(rank + ((E + 1) & ~1));           // 256
    float* normIf  = (float*)(bsum + 256);                    // N
    float* normOf  = normIf + N;                              // N
    size_t iend = (size_t)(normOf + N - (float*)d_ws);
    size_t wofs = (iend * 4 + 15) & ~(size_t)15;
    short* Wbf = (short*)((char*)d_ws + wofs);                // 98304 bf16
    size_t fofs = (wofs + 98304 * 2 + 15) & ~(size_t)15;
    short* fh = (short*)((char*)d_ws + fofs);                 // N*256 bf16
    // total ws: ~45 MB (proven-safe budget: 51.6 MB)
    short* agg = (short*)d_out;  // bf16 agg aliased over d_out

    k_hist<<<2 * NCH, 1024, 0, stream>>>(src, dst, partO, partI, rank,
                                         N, Npad, E, chunk);
    k_bsum<<<NB, 256, 0, stream>>>(partI, bsum, N, Npad);
    k_off<<<NB, 256, 0, stream>>>(partI, partO, bsum, csrOffC, csrOff,
                                  normIf, normOf, N, Npad, NB);
    k_xcw<<<(N * 64 + 98304 + E + 255) / 256, 256, 0, stream>>>(
        feat, hx, Wi, Wh, normOf, Wbf, fh,
        src, dst, rank, csrOffC, srcSorted, N, E, chunk);

    gather_kernel<<<(N + 3) / 4, 256, 0, stream>>>(
        fh, csrOff, srcSorted, normIf, agg, N);
    gemm_gates_kernel<<<(N + 63) / 64, 256, 0, stream>>>(
        agg, hx, Wbf, bi, bh, out, N);
}

// Round 9
// 246.209 us; speedup vs baseline: 1.3739x; 1.0195x over previous
//
#include <hip/hip_runtime.h>
#include <math.h>

#define DIM 128
#define NCH 32          // edge chunks; per-chunk per-node count < 65536 -> u16
#define NMAXW 25024     // LDS histogram words (covers N <= 50048)

typedef float f32x4v __attribute__((ext_vector_type(4)));
typedef short bf16x8 __attribute__((ext_vector_type(8)));

static __device__ __forceinline__ short f2bf(float f) {
    unsigned u = __float_as_uint(f);
    unsigned r = (u + 0x7fffu + ((u >> 16) & 1u)) >> 16;   // RNE
    return (short)r;
}
static __device__ __forceinline__ float bf2f(unsigned short s) {
    return __uint_as_float(((unsigned)s) << 16);
}

// ---------------------------------------------------------------------------
// K1: ONE-PASS full-N LDS histogram per edge chunk (u16 packed counters).
// Per-chunk counts < 65536 -> full-N u16 histogram = 100 KB LDS. Packed u16
// atomics on u32 words (halves can't carry: each half < 2^16). Blocks
// [0,NCH): dst histogram + rank (dense coalesced u16 write); [NCH,2NCH):
// src histogram. Edge reads: 6.4 MB, once.
__global__ __launch_bounds__(1024) void k_hist(const int* __restrict__ src,
                                               const int* __restrict__ dst,
                                               unsigned short* __restrict__ partO,
                                               unsigned short* __restrict__ partI,
                                               unsigned short* __restrict__ rank,
                                               int N, int Npad, int E, int chunk) {
    __shared__ unsigned int h[NMAXW];
    int t = threadIdx.x;
    int isI = blockIdx.x < NCH;
    int c = isI ? blockIdx.x : blockIdx.x - NCH;
    int NW = (N + 1) >> 1;
    for (int i = t; i < NW; i += 1024) h[i] = 0;
    __syncthreads();
    int e0 = c * chunk, e1 = min(e0 + chunk, E);
    if (isI) {
        for (int e = e0 + t; e < e1; e += 1024) {
            int d = dst[e];
            unsigned sh = (d & 1) * 16;
            unsigned old = atomicAdd(&h[d >> 1], 1u << sh);   // LDS atomic
            rank[e] = (unsigned short)((old >> sh) & 0xffffu);
        }
    } else {
        for (int e = e0 + t; e < e1; e += 1024) {
            int s = src[e];
            atomicAdd(&h[s >> 1], 1u << ((s & 1) * 16));
        }
    }
    __syncthreads();
    unsigned int* p = (unsigned int*)((isI ? partI : partO) + (size_t)c * Npad);
    for (int i = t; i < NW; i += 1024) p[i] = h[i];   // u16 pair per word
}

// K2: per-256-node block sums of degI (over the NCH chunk partials).
__global__ __launch_bounds__(256) void k_bsum(const unsigned short* __restrict__ partI,
                                              int* __restrict__ bsum, int N, int Npad) {
    __shared__ int red[4];
    int b = blockIdx.x, t = threadIdx.x;
    int n = b * 256 + t;
    int s = 0;
    if (n < N) {
        #pragma unroll
        for (int c = 0; c < NCH; ++c) s += partI[(size_t)c * Npad + n];
    }
    for (int off = 32; off; off >>= 1) s += __shfl_down(s, off);
    if ((t & 63) == 0) red[t >> 6] = s;
    __syncthreads();
    if (t == 0) bsum[b] = red[0] + red[1] + red[2] + red[3];
}

// K3: exclusive scan -> csrOff + per-chunk bases csrOffC + norm factors.
// One node per thread, NB <= 256 blocks, LDS Hillis-Steele scans.
__global__ __launch_bounds__(256) void k_off(const unsigned short* __restrict__ partI,
                                             const unsigned short* __restrict__ partO,
                                             const int* __restrict__ bsum,
                                             int* __restrict__ csrOffC,
                                             int* __restrict__ csrOff,
                                             float* __restrict__ normIf,
                                             float* __restrict__ normOf,
                                             int N, int Npad, int NB) {
    __shared__ int sp[256];
    __shared__ int sbase;
    int b = blockIdx.x, t = threadIdx.x;
    int own = (t < NB) ? bsum[t] : 0;
    sp[t] = own;
    __syncthreads();
    for (int off = 1; off < 256; off <<= 1) {
        int u = (t >= off) ? sp[t - off] : 0;
        __syncthreads();
        sp[t] += u;
        __syncthreads();
    }
    if (t == b) sbase = sp[t] - own;
    if (b == 0 && t == NB - 1) csrOff[N] = sp[t];
    __syncthreads();
    int n = b * 256 + t;
    int cv[NCH];
    int tI = 0, tO = 0;
    if (n < N) {
        #pragma unroll
        for (int c = 0; c < NCH; ++c) {
            cv[c] = partI[(size_t)c * Npad + n];
            tI += cv[c];
            tO += partO[(size_t)c * Npad + n];
        }
    }
    sp[t] = tI;
    __syncthreads();
    for (int off = 1; off < 256; off <<= 1) {
        int u = (t >= off) ? sp[t - off] : 0;
        __syncthreads();
        sp[t] += u;
        __syncthreads();
    }
    int o = sbase + sp[t] - tI;
    if (n < N) {
        csrOff[n] = o;
        normIf[n] = rsqrtf(fmaxf((float)tI, 1.0f));
        normOf[n] = rsqrtf(fmaxf((float)tO, 1.0f));
        int base = o;
        #pragma unroll
        for (int c = 0; c < NCH; ++c) {
            csrOffC[(size_t)c * N + n] = base;
            base += cv[c];
        }
    }
}

// K4: merged pre-scaled bf16 feat/hx + bf16 weight convert (fill split out
// this round for rocprof visibility of the scatter cost).
__global__ __launch_bounds__(256) void k_xcw(const float* __restrict__ feat,
                                             const float* __restrict__ hx,
                                             const float* __restrict__ Wi,
                                             const float* __restrict__ Wh,
                                             const float* __restrict__ normOf,
                                             short* __restrict__ Wbf,
                                             short* __restrict__ fh, int N) {
    int i = blockIdx.x * 256 + threadIdx.x;
    int T1 = N * 64;
    if (i < T1) {
        int n = i >> 6, q = i & 63;
        float ns = normOf[n];
        const float* spp = (q < 32) ? &feat[(size_t)n * 128 + q * 4]
                                    : &hx[(size_t)n * 128 + (q - 32) * 4];
        float4 v = *(const float4*)spp;
        short4 p;
        p.x = f2bf(v.x * ns); p.y = f2bf(v.y * ns);
        p.z = f2bf(v.z * ns); p.w = f2bf(v.w * ns);
        *(short4*)&fh[(size_t)n * 256 + q * 4] = p;   // q*4 == 128+(q-32)*4
    } else {
        int w = i - T1;
        if (w < 98304) {
            int k = w & 127, n = (w >> 7) & 15, r = w >> 11;
            int gm = r % 6, cb = r / 6;
            const float* Wsrc = (gm < 3) ? Wi : Wh;
            int g = gm % 3;
            Wbf[w] = f2bf(Wsrc[k * 384 + g * 128 + cb * 16 + n]);
        }
    }
}

// K5: atomic-free counting-sort fill (pos = csrOffC[e/chunk][dst] + rank).
// Separate kernel: suspected scatter write-amplification (sub-line writes to
// the same 64B line from many XCDs -> RFO ping-pong) — measure it directly.
__global__ __launch_bounds__(256) void k_fill(const int* __restrict__ src,
                                              const int* __restrict__ dst,
                                              const unsigned short* __restrict__ rank,
                                              const int* __restrict__ csrOffC,
                                              int* __restrict__ srcSorted,
                                              int N, int E, int chunk) {
    int e = blockIdx.x * 256 + threadIdx.x;
    if (e < E) {
        int c = e / chunk;
        int pos = csrOffC[(size_t)c * N + dst[e]] + (int)rank[e];
        srcSorted[pos] = src[e];
    }
}

// ---------------------------------------------------------------------------
// K6: gather-aggregate. One wave per dst node, no LDS, 8 B/lane row reads,
// wave-uniform scalar index loads. R1 structure — proven floor (~65 us)
// across R1/R2/R3/R7; every MLP-raising rewrite (half-wave split, explicit
// batch, shfl-broadcast) was neutral or regressed. Do not touch.
__global__ __launch_bounds__(256) void gather_kernel(
    const short* __restrict__ fh, const int* __restrict__ csrOff,
    const int* __restrict__ srcSorted, const float* __restrict__ normIf,
    short* __restrict__ agg, int N) {
    int wv = threadIdx.x >> 6, lane = threadIdx.x & 63;
    int d = blockIdx.x * 4 + wv;
    if (d >= N) return;
    const ushort4* fh4 = (const ushort4*)fh;
    int beg = csrOff[d], end = csrOff[d + 1];
    float4 acc = make_float4(0.f, 0.f, 0.f, 0.f);
    #pragma unroll 8
    for (int e = beg; e < end; ++e) {
        int s = srcSorted[e];                     // wave-uniform scalar load
        ushort4 v = fh4[(size_t)s * 64 + lane];   // 8B/lane, 512B/wave
        acc.x += bf2f(v.x); acc.y += bf2f(v.y);
        acc.z += bf2f(v.z); acc.w += bf2f(v.w);
    }
    float nd = normIf[d];
    short4 p;
    p.x = f2bf(acc.x * nd); p.y = f2bf(acc.y * nd);
    p.z = f2bf(acc.z * nd); p.w = f2bf(acc.w * nd);
    *(short4*)&agg[(size_t)d * 256 + lane * 4] = p;
}

// ---------------------------------------------------------------------------
// K7: dense bf16 MFMA GEMM + GRU gates. Weights staged per-cb into LDS via
// global_load_lds (width=16), double-buffered, XOR-swizzled (16B slot ^=
// row&15) on both sides -> conflict-free ds_read_b128.
// NEW (this round): the per-cb hv (hx) and bias loads are HOISTED to the top
// of the cb body, before the MFMA cluster. Previously the ~600cy hv load sat
// on the serial epilogue chain (8x per wave at only ~3 waves/SIMD of TLP);
// issued early, its latency hides under 24 MFMAs + staging.
#define GLOAD_LDS16(gp, lp)                                                   \
    __builtin_amdgcn_global_load_lds(                                         \
        (const __attribute__((address_space(1))) void*)(gp),                  \
        (__attribute__((address_space(3))) void*)(lp), 16, 0, 0)

__global__ __launch_bounds__(256, 3) void gemm_gates_kernel(
    const short* __restrict__ agg, const float* __restrict__ hx,
    const short* __restrict__ Wbf,
    const float* __restrict__ bi, const float* __restrict__ bh,
    float* __restrict__ out, int N) {
    __shared__ short wlds[2][12288];            // 2 x 24.6 KB double buffer
    const int tid = threadIdx.x;
    const int wv = tid >> 6, lane = tid & 63;
    const int l15 = lane & 15, quad = lane >> 4;
    const int rowBase = (blockIdx.x * 4 + wv) * 16;
    const bool active = rowBase < N;   // N % 16 == 0: active waves fully valid

    // A-fragments preloaded to registers BEFORE any out store (agg aliases
    // out; each wave reads/writes only its own 16 rows -> no hazard).
    int arow = active ? rowBase + l15 : 0;
    const short* aPtr = agg + (size_t)arow * 256;
    bf16x8 aLo[4], aHi[4];
    #pragma unroll
    for (int kst = 0; kst < 4; ++kst) {
        aLo[kst] = *(const bf16x8*)&aPtr[kst * 32 + quad * 8];
        aHi[kst] = *(const bf16x8*)&aPtr[128 + kst * 32 + quad * 8];
    }

    // Prologue: stage cb=0 slab (each wave copies its own 6144 B chunk).
    {
        const char* gs = (const char*)Wbf;
        #pragma unroll
        for (int i = 0; i < 6; ++i) {
            int ldsByte = wv * 6144 + i * 1024 + lane * 16;
            int gByte = ldsByte ^ (((ldsByte >> 8) & 15) << 4);   // slot ^= row&15
            GLOAD_LDS16(gs + gByte, (char*)&wlds[0][0] + wv * 6144 + i * 1024);
        }
    }
    __syncthreads();   // compiler drains vmcnt(0) before s_barrier

    for (int cb = 0; cb < 8; ++cb) {
        const int buf = cb & 1;
        if (cb < 7) {   // async prefetch next slab into the other buffer
            const char* gs = (const char*)(Wbf + (size_t)(cb + 1) * 12288);
            #pragma unroll
            for (int i = 0; i < 6; ++i) {
                int ldsByte = wv * 6144 + i * 1024 + lane * 16;
                int gByte = ldsByte ^ (((ldsByte >> 8) & 15) << 4);
                GLOAD_LDS16(gs + gByte,
                            (char*)&wlds[buf ^ 1][0] + wv * 6144 + i * 1024);
            }
        }
        if (active) {
            // Hoisted epilogue operands: issue loads before the MFMA cluster
            // so their latency hides under the matrix work.
            int ocol = cb * 16 + l15;
            float hv[4];
            #pragma unroll
            for (int reg = 0; reg < 4; ++reg)
                hv[reg] = hx[(size_t)(rowBase + quad * 4 + reg) * DIM + ocol];
            float bir = bi[ocol], biz = bi[128 + ocol], bin = bi[256 + ocol];
            float bhr = bh[ocol], bhz = bh[128 + ocol], bhn = bh[256 + ocol];

            f32x4v acc[6];
            #pragma unroll
            for (int g = 0; g < 6; ++g) acc[g] = (f32x4v){0.f, 0.f, 0.f, 0.f};
            const char* slab = (const char*)&wlds[buf][0];
            #pragma unroll
            for (int kst = 0; kst < 4; ++kst) {
                const int co = (((kst * 4 + quad) ^ l15) << 4);   // swizzled col
                #pragma unroll
                for (int g = 0; g < 3; ++g) {
                    bf16x8 bI = *(const bf16x8*)(slab + g * 4096 + l15 * 256 + co);
                    acc[g] = __builtin_amdgcn_mfma_f32_16x16x32_bf16(
                        aLo[kst], bI, acc[g], 0, 0, 0);
                    bf16x8 bH = *(const bf16x8*)(slab + (g + 3) * 4096 + l15 * 256 + co);
                    acc[g + 3] = __builtin_amdgcn_mfma_f32_16x16x32_bf16(
                        aHi[kst], bH, acc[g + 3], 0, 0, 0);
                }
            }
            #pragma unroll
            for (int reg = 0; reg < 4; ++reg) {
                int row = rowBase + quad * 4 + reg;
                float ir = acc[0][reg] + bir, iz = acc[1][reg] + biz, in_ = acc[2][reg] + bin;
                float hr = acc[3][reg] + bhr, hz = acc[4][reg] + bhz, hn = acc[5][reg] + bhn;
                float rg = 1.0f / (1.0f + __expf(-(ir + hr)));
                float zg = 1.0f / (1.0f + __expf(-(iz + hz)));
                float ng = tanhf(in_ + rg * hn);
                out[(size_t)row * DIM + ocol] = (1.0f - zg) * ng + zg * hv[reg];
            }
        }
        __syncthreads();   // drains this iter's prefetch; protects buf reuse
    }
}

// ---------------------------------------------------------------------------
extern "C" void kernel_launch(void* const* d_in, const int* in_sizes, int n_in,
                              void* d_out, int out_size, void* d_ws, size_t ws_size,
                              hipStream_t stream) {
    const float* feat = (const float*)d_in[0];
    const float* hx   = (const float*)d_in[1];
    const float* Wi   = (const float*)d_in[2];
    const float* bi   = (const float*)d_in[3];
    const float* Wh   = (const float*)d_in[4];
    const float* bh   = (const float*)d_in[5];
    const int* src    = (const int*)d_in[6];
    const int* dst    = (const int*)d_in[7];
    float* out        = (float*)d_out;

    int N = in_sizes[0] / DIM;   // 50000
    int E = in_sizes[6];         // 800000
    int Npad = (N + 1) & ~1;     // even stride for u16-pair word copies
    int chunk = (E + NCH - 1) / NCH;     // 25000 (< 65536 -> u16 counters)
    int NB    = (N + 255) / 256;         // 196 (<= 256 for the LDS scan)

    unsigned short* partI = (unsigned short*)d_ws;            // NCH*Npad u16
    unsigned short* partO = partI + (size_t)NCH * Npad;       // NCH*Npad u16
    int* csrOffC   = (int*)(partO + (size_t)NCH * Npad);      // NCH*N
    int* csrOff    = csrOffC + (size_t)NCH * N;               // N+1
    int* srcSorted = csrOff + N + 1;                          // E
    unsigned short* rank = (unsigned short*)(srcSorted + E);  // E u16
    int* bsum      = (int*)(rank + ((E + 1) & ~1));           // 256
    float* normIf  = (float*)(bsum + 256);                    // N
    float* normOf  = normIf + N;                              // N
    size_t iend = (size_t)(normOf + N - (float*)d_ws);
    size_t wofs = (iend * 4 + 15) & ~(size_t)15;
    short* Wbf = (short*)((char*)d_ws + wofs);                // 98304 bf16
    size_t fofs = (wofs + 98304 * 2 + 15) & ~(size_t)15;
    short* fh = (short*)((char*)d_ws + fofs);                 // N*256 bf16
    // total ws: ~45 MB (proven-safe budget: 51.6 MB)
    short* agg = (short*)d_out;  // bf16 agg aliased over d_out

    k_hist<<<2 * NCH, 1024, 0, stream>>>(src, dst, partO, partI, rank,
                                         N, Npad, E, chunk);
    k_bsum<<<NB, 256, 0, stream>>>(partI, bsum, N, Npad);
    k_off<<<NB, 256, 0, stream>>>(partI, partO, bsum, csrOffC, csrOff,
                                  normIf, normOf, N, Npad, NB);
    k_xcw<<<(N * 64 + 98304 + 255) / 256, 256, 0, stream>>>(
        feat, hx, Wi, Wh, normOf, Wbf, fh, N);
    k_fill<<<(E + 255) / 256, 256, 0, stream>>>(
        src, dst, rank, csrOffC, srcSorted, N, E, chunk);

    gather_kernel<<<(N + 3) / 4, 256, 0, stream>>>(
        fh, csrOff, srcSorted, normIf, agg, N);
    gemm_gates_kernel<<<(N + 63) / 64, 256, 0, stream>>>(
        agg, hx, Wbf, bi, bh, out, N);
}